// Round 2
// baseline (239.973 us; speedup 1.0000x reference)
//
#include <hip/hip_runtime.h>
#include <hip/hip_bf16.h>
#include <stdint.h>

#define B_ 2
#define S_ 2048
#define D_ 1024
#define H_ 16
#define HD_ 64
#define M_ (B_*S_)        // 4096 rows
#define NQKV_ (H_*3*HD_)  // 3072

typedef __attribute__((ext_vector_type(8))) short short8;
typedef __attribute__((ext_vector_type(4))) float f32x4;
typedef unsigned short u16;
typedef unsigned int u32;

__device__ __forceinline__ u16 f2b(float f){
  u32 u = __float_as_uint(f);
  u32 r = (u + 0x7FFFu + ((u >> 16) & 1u)) >> 16;   // RNE f32->bf16
  return (u16)r;
}

__device__ __forceinline__ void gl_lds16(const void* g, void* l){
  __builtin_amdgcn_global_load_lds(
      (const __attribute__((address_space(1))) void*)g,
      (__attribute__((address_space(3))) void*)l, 16, 0, 0);
}

// ---------------- LayerNorm: f32 [4096][1024] -> bf16 ----------------
__global__ __launch_bounds__(256) void ln_kernel(const float* __restrict__ x,
    const float* __restrict__ gam, const float* __restrict__ bet, u16* __restrict__ xn){
  int row = blockIdx.x;
  const float4* xr = (const float4*)(x + (size_t)row * D_);
  float4 v = xr[threadIdx.x];
  float s = v.x + v.y + v.z + v.w;
  float q = v.x*v.x + v.y*v.y + v.z*v.z + v.w*v.w;
  #pragma unroll
  for(int o = 32; o > 0; o >>= 1){ s += __shfl_down(s, o); q += __shfl_down(q, o); }
  __shared__ float red[8];
  int w = threadIdx.x >> 6, lane = threadIdx.x & 63;
  if(lane == 0){ red[w] = s; red[4+w] = q; }
  __syncthreads();
  float st = red[0]+red[1]+red[2]+red[3];
  float qt = red[4]+red[5]+red[6]+red[7];
  float mu = st * (1.0f / D_);
  float inv = rsqrtf(qt * (1.0f / D_) - mu*mu + 1e-6f);
  float4 g = ((const float4*)gam)[threadIdx.x];
  float4 b = ((const float4*)bet)[threadIdx.x];
  ushort4 o4;
  o4.x = f2b((v.x-mu)*inv*g.x + b.x);
  o4.y = f2b((v.y-mu)*inv*g.y + b.y);
  o4.z = f2b((v.z-mu)*inv*g.z + b.z);
  o4.w = f2b((v.w-mu)*inv*g.w + b.w);
  ((ushort4*)(xn + (size_t)row * D_))[threadIdx.x] = o4;
}

// ------- transpose+convert: src f32 [R][C] -> dst bf16 [C][R] -------
__global__ __launch_bounds__(256) void tconv_kernel(const float* __restrict__ src,
    u16* __restrict__ dst, int R, int C){
  __shared__ float tile[64][65];
  int tx = threadIdx.x & 63, ty = threadIdx.x >> 6;
  int r0 = blockIdx.y * 64, c0 = blockIdx.x * 64;
  #pragma unroll
  for(int i = 0; i < 16; i++){
    int r = ty*16 + i;
    tile[r][tx] = src[(size_t)(r0+r)*C + c0 + tx];
  }
  __syncthreads();
  #pragma unroll
  for(int i = 0; i < 16; i++){
    int r = ty*16 + i;
    dst[(size_t)(c0+r)*R + r0 + tx] = f2b(tile[tx][r]);
  }
}

// ------- V [BH][S][HD] bf16 -> Vt [BH][HD][S] bf16 -------
__global__ __launch_bounds__(256) void vtrans_kernel(const u16* __restrict__ V, u16* __restrict__ Vt){
  __shared__ u16 t2[64][66];
  int tx = threadIdx.x & 63, ty = threadIdx.x >> 6;
  int bh = blockIdx.y, s0 = blockIdx.x * 64;
  const u16* src = V + (size_t)bh * S_ * HD_;
  u16* dst = Vt + (size_t)bh * HD_ * S_;
  #pragma unroll
  for(int i = 0; i < 16; i++){
    int r = ty*16 + i;
    t2[r][tx] = src[(size_t)(s0+r)*HD_ + tx];
  }
  __syncthreads();
  #pragma unroll
  for(int i = 0; i < 16; i++){
    int hd = ty*16 + i;
    dst[(size_t)hd*S_ + s0 + tx] = t2[tx][hd];
  }
}

// ------- GEMM (m97 structure): A [M][K] bf16 x Bt [N][K] bf16 -------
// MODE 0: epilogue scatters to Q (x0.125), K, V in [B,H,S,HD] bf16; bias = b_qkv[col]
// MODE 1: epilogue writes f32 out[row*N+col] + bias[col]   (d_out is float!)
template<int MODE>
__global__ __launch_bounds__(256) void gemm_kernel(const u16* __restrict__ A,
    const u16* __restrict__ Bt, const float* __restrict__ bias,
    u16* __restrict__ o0, u16* __restrict__ o1, u16* __restrict__ o2,
    int K, int N){
  __shared__ u16 As[128*32];
  __shared__ u16 Bs[128*32];
  int tid = threadIdx.x, w = tid >> 6, lane = tid & 63;
  int m0 = blockIdx.y * 128, n0 = blockIdx.x * 128;
  int wm = w >> 1, wn = w & 1;
  f32x4 z = {0.f, 0.f, 0.f, 0.f};
  f32x4 acc[4][4];
  #pragma unroll
  for(int r = 0; r < 4; r++)
    #pragma unroll
    for(int c = 0; c < 4; c++) acc[r][c] = z;
  int srow = lane >> 2, sch = (lane & 3) * 8;
  const u16* Ag = A + (size_t)m0 * K + (size_t)srow * K + sch;
  const u16* Bg = Bt + (size_t)n0 * K + (size_t)srow * K + sch;
  for(int kt = 0; kt < K; kt += 32){
    __syncthreads();
    #pragma unroll
    for(int i = 0; i < 2; i++){
      int rb = w*32 + i*16;
      gl_lds16(Ag + (size_t)rb*K + kt, &As[rb*32]);
      gl_lds16(Bg + (size_t)rb*K + kt, &Bs[rb*32]);
    }
    __syncthreads();
    int kc = (lane >> 4) * 8;
    int ar = wm*64 + (lane & 15);
    int bc = wn*64 + (lane & 15);
    short8 af[4], bfr[4];
    #pragma unroll
    for(int r = 0; r < 4; r++) af[r] = *(const short8*)&As[(ar + r*16)*32 + kc];
    #pragma unroll
    for(int c = 0; c < 4; c++) bfr[c] = *(const short8*)&Bs[(bc + c*16)*32 + kc];
    #pragma unroll
    for(int r = 0; r < 4; r++)
      #pragma unroll
      for(int c = 0; c < 4; c++)
        acc[r][c] = __builtin_amdgcn_mfma_f32_16x16x32_bf16(af[r], bfr[c], acc[r][c], 0, 0, 0);
  }
  #pragma unroll
  for(int r = 0; r < 4; r++){
    #pragma unroll
    for(int c = 0; c < 4; c++){
      #pragma unroll
      for(int q = 0; q < 4; q++){
        int row = m0 + wm*64 + r*16 + (lane >> 4)*4 + q;
        int col = n0 + wn*64 + c*16 + (lane & 15);
        float v = acc[r][c][q] + bias[col];
        if(MODE == 0){
          int h = col / 192, rr = col - h*192;
          int b = row >> 11, s = row & (S_ - 1);
          size_t base = ((size_t)(b*H_ + h)*S_ + s) * HD_;
          if(rr < 64)        o0[base + rr]       = f2b(v * 0.125f);
          else if(rr < 128)  o1[base + rr - 64]  = f2b(v);
          else               o2[base + rr - 128] = f2b(v);
        } else {
          ((float*)o0)[(size_t)row * N + col] = v;   // f32 final output
        }
      }
    }
  }
}

// ------- causal flash attention: Q,K [BH][S][HD], Vt [BH][HD][S] -> O [B,S,H,HD] bf16 -------
__global__ __launch_bounds__(256) void attn_kernel(const u16* __restrict__ Q,
    const u16* __restrict__ Kb, const u16* __restrict__ Vt, u16* __restrict__ O){
  __shared__ u16 Ks[64*64];
  __shared__ u16 Vs[64*64];
  __shared__ u16 Ps[4*16*64];
  int tid = threadIdx.x, w = tid >> 6, lane = tid & 63;
  int qt = blockIdx.x, bh = blockIdx.y;
  int q0 = qt * 64;
  const u16* Qg = Q + (size_t)bh * S_ * HD_;
  const u16* Kg = Kb + (size_t)bh * S_ * HD_;
  const u16* Vg = Vt + (size_t)bh * HD_ * S_;
  int qrow = q0 + w*16 + (lane & 15);
  short8 qf[2];
  #pragma unroll
  for(int c = 0; c < 2; c++)
    qf[c] = *(const short8*)(Qg + (size_t)qrow*HD_ + (lane >> 4)*8 + c*32);
  f32x4 z = {0.f, 0.f, 0.f, 0.f};
  f32x4 o[4];
  float m_run[4], l_run[4];
  #pragma unroll
  for(int i = 0; i < 4; i++){ o[i] = z; m_run[i] = -1e30f; l_run[i] = 0.f; }
  int svrow = lane >> 3;   // 0..7
  int scb = lane & 7;      // 16B chunk within 128B row
  int ntiles = qt + 1;
  for(int kt = 0; kt < ntiles; kt++){
    int kv0 = kt * 64;
    __syncthreads();                       // prev tile fully consumed
    #pragma unroll
    for(int i = 0; i < 2; i++){
      int rb = (i*4 + w) * 8;
      int row = rb + svrow;
      int cbs = scb ^ (row & 7);           // pre-swizzled global source (linear LDS dest)
      gl_lds16(Kg + (size_t)(kv0 + row)*HD_ + cbs*8, &Ks[rb*64]);
      gl_lds16(Vg + (size_t)row*S_ + kv0 + cbs*8, &Vs[rb*64]);
    }
    __syncthreads();                       // staged data visible
    // S = (Q*scale) K^T  — per-wave 16 q-rows x 64 kv-cols
    f32x4 sf[4];
    #pragma unroll
    for(int j = 0; j < 4; j++){
      f32x4 acc = z;
      #pragma unroll
      for(int c = 0; c < 2; c++){
        int row = j*16 + (lane & 15);
        int kc16 = (lane >> 4) + c*4;
        short8 kf = *(const short8*)((const char*)Ks + row*128 + ((kc16 ^ (row & 7)) * 16));
        acc = __builtin_amdgcn_mfma_f32_16x16x32_bf16(qf[c], kf, acc, 0, 0, 0);
      }
      sf[j] = acc;
    }
    if(kt == qt){                          // diagonal tile: causal mask
      #pragma unroll
      for(int j = 0; j < 4; j++){
        int colk = kv0 + j*16 + (lane & 15);
        #pragma unroll
        for(int q = 0; q < 4; q++){
          int rowq = q0 + w*16 + (lane >> 4)*4 + q;
          if(colk > rowq) sf[j][q] = -1e30f;
        }
      }
    }
    // online softmax (rows live in 16-lane groups)
    float al[4];
    float p[4][4];
    #pragma unroll
    for(int q = 0; q < 4; q++){
      float m = fmaxf(fmaxf(sf[0][q], sf[1][q]), fmaxf(sf[2][q], sf[3][q]));
      #pragma unroll
      for(int off = 1; off < 16; off <<= 1) m = fmaxf(m, __shfl_xor(m, off));
      float mn = fmaxf(m_run[q], m);
      al[q] = __expf(m_run[q] - mn);
      m_run[q] = mn;
      float sum = 0.f;
      #pragma unroll
      for(int j = 0; j < 4; j++){ p[j][q] = __expf(sf[j][q] - mn); sum += p[j][q]; }
      #pragma unroll
      for(int off = 1; off < 16; off <<= 1) sum += __shfl_xor(sum, off);
      l_run[q] = l_run[q]*al[q] + sum;
    }
    #pragma unroll
    for(int n = 0; n < 4; n++)
      #pragma unroll
      for(int q = 0; q < 4; q++) o[n][q] *= al[q];
    // P -> swizzled LDS (per-wave buffer), transposes C-layout to A-frag layout
    char* Pw = (char*)Ps + w*2048;
    #pragma unroll
    for(int j = 0; j < 4; j++)
      #pragma unroll
      for(int q = 0; q < 4; q++){
        int row = (lane >> 4)*4 + q;
        int colb = (j*16 + (lane & 15)) * 2;
        *(u16*)(Pw + ((row*128 + colb) ^ ((row & 7) << 4))) = f2b(p[j][q]);
      }
    __syncthreads();                       // write->read ordering
    // O += P V
    #pragma unroll
    for(int c = 0; c < 2; c++){
      int prow = lane & 15;
      int kb = ((lane >> 4) + c*4) * 16;
      short8 pa = *(const short8*)((const char*)Ps + w*2048 + ((prow*128 + kb) ^ ((prow & 7) << 4)));
      #pragma unroll
      for(int n = 0; n < 4; n++){
        int vrow = n*16 + (lane & 15);
        int kc16 = (lane >> 4) + c*4;
        short8 vf = *(const short8*)((const char*)Vs + vrow*128 + ((kc16 ^ (vrow & 7)) * 16));
        o[n] = __builtin_amdgcn_mfma_f32_16x16x32_bf16(pa, vf, o[n], 0, 0, 0);
      }
    }
  }
  int b = bh >> 4, h = bh & 15;
  float inv[4];
  #pragma unroll
  for(int q = 0; q < 4; q++) inv[q] = 1.f / l_run[q];
  #pragma unroll
  for(int n = 0; n < 4; n++)
    #pragma unroll
    for(int q = 0; q < 4; q++){
      int s = q0 + w*16 + (lane >> 4)*4 + q;
      int hd = n*16 + (lane & 15);
      O[(((size_t)(b*S_ + s))*H_ + h)*HD_ + hd] = f2b(o[n][q] * inv[q]);
    }
}

extern "C" void kernel_launch(void* const* d_in, const int* in_sizes, int n_in,
                              void* d_out, int out_size, void* d_ws, size_t ws_size,
                              hipStream_t stream){
  (void)in_sizes; (void)n_in; (void)out_size; (void)ws_size;
  const float* x    = (const float*)d_in[0];
  const float* gam  = (const float*)d_in[1];
  const float* bet  = (const float*)d_in[2];
  const float* wqkv = (const float*)d_in[3];
  const float* bqkv = (const float*)d_in[4];
  const float* wout = (const float*)d_in[5];
  const float* bout = (const float*)d_in[6];
  char* ws = (char*)d_ws;
  // layout (bytes): xn 8.4M | wqkvT 6.3M | woutT 2.1M | Q 8.4M | K 8.4M | V 8.4M | Vt 8.4M
  u16* xn    = (u16*)(ws);
  u16* wqkvT = (u16*)(ws + 8388608);
  u16* woutT = (u16*)(ws + 8388608 + 6291456);
  u16* Qb    = (u16*)(ws + 16777216);
  u16* Kb    = (u16*)(ws + 16777216 + 8388608);
  u16* Vb    = (u16*)(ws + 16777216 + 2*8388608);
  u16* Vt    = (u16*)(ws + 16777216 + 3*8388608);
  u16* attnb = xn;                      // xn dead after GEMM1 -> reuse
  float* out = (float*)d_out;           // f32 output (reference dtype = float32)

  ln_kernel<<<dim3(M_), dim3(256), 0, stream>>>(x, gam, bet, xn);
  tconv_kernel<<<dim3(NQKV_/64, D_/64), dim3(256), 0, stream>>>(wqkv, wqkvT, D_, NQKV_);
  tconv_kernel<<<dim3(D_/64, D_/64), dim3(256), 0, stream>>>(wout, woutT, D_, D_);
  gemm_kernel<0><<<dim3(NQKV_/128, M_/128), dim3(256), 0, stream>>>(xn, wqkvT, bqkv, Qb, Kb, Vb, D_, NQKV_);
  vtrans_kernel<<<dim3(S_/64, B_*H_), dim3(256), 0, stream>>>(Vb, Vt);
  attn_kernel<<<dim3(S_/64, B_*H_), dim3(256), 0, stream>>>(Qb, Kb, Vt, attnb);
  gemm_kernel<1><<<dim3(D_/128, M_/128), dim3(256), 0, stream>>>(attnb, woutT, bout, (u16*)out, nullptr, nullptr, D_, D_);
}

// Round 3
// 178.071 us; speedup vs baseline: 1.3476x; 1.3476x over previous
//
#include <hip/hip_runtime.h>
#include <hip/hip_bf16.h>
#include <stdint.h>

#define B_ 2
#define S_ 2048
#define D_ 1024
#define H_ 16
#define HD_ 64
#define M_ (B_*S_)        // 4096 rows
#define NQKV_ (H_*3*HD_)  // 3072

typedef __attribute__((ext_vector_type(8))) short short8;
typedef __attribute__((ext_vector_type(4))) float f32x4;
typedef unsigned short u16;
typedef unsigned int u32;

__device__ __forceinline__ u16 f2b(float f){
  u32 u = __float_as_uint(f);
  u32 r = (u + 0x7FFFu + ((u >> 16) & 1u)) >> 16;   // RNE f32->bf16
  return (u16)r;
}

__device__ __forceinline__ void gl_lds16(const void* g, void* l){
  __builtin_amdgcn_global_load_lds(
      (const __attribute__((address_space(1))) void*)g,
      (__attribute__((address_space(3))) void*)l, 16, 0, 0);
}

// ---------------- LayerNorm: f32 [4096][1024] -> bf16 ----------------
__global__ __launch_bounds__(256) void ln_kernel(const float* __restrict__ x,
    const float* __restrict__ gam, const float* __restrict__ bet, u16* __restrict__ xn){
  int row = blockIdx.x;
  const float4* xr = (const float4*)(x + (size_t)row * D_);
  float4 v = xr[threadIdx.x];
  float s = v.x + v.y + v.z + v.w;
  float q = v.x*v.x + v.y*v.y + v.z*v.z + v.w*v.w;
  #pragma unroll
  for(int o = 32; o > 0; o >>= 1){ s += __shfl_down(s, o); q += __shfl_down(q, o); }
  __shared__ float red[8];
  int w = threadIdx.x >> 6, lane = threadIdx.x & 63;
  if(lane == 0){ red[w] = s; red[4+w] = q; }
  __syncthreads();
  float st = red[0]+red[1]+red[2]+red[3];
  float qt = red[4]+red[5]+red[6]+red[7];
  float mu = st * (1.0f / D_);
  float inv = rsqrtf(qt * (1.0f / D_) - mu*mu + 1e-6f);
  float4 g = ((const float4*)gam)[threadIdx.x];
  float4 b = ((const float4*)bet)[threadIdx.x];
  ushort4 o4;
  o4.x = f2b((v.x-mu)*inv*g.x + b.x);
  o4.y = f2b((v.y-mu)*inv*g.y + b.y);
  o4.z = f2b((v.z-mu)*inv*g.z + b.z);
  o4.w = f2b((v.w-mu)*inv*g.w + b.w);
  ((ushort4*)(xn + (size_t)row * D_))[threadIdx.x] = o4;
}

// ------- transpose+convert: src f32 [R][C] -> dst bf16 [C][R] -------
__global__ __launch_bounds__(256) void tconv_kernel(const float* __restrict__ src,
    u16* __restrict__ dst, int R, int C){
  __shared__ float tile[64][65];
  int tx = threadIdx.x & 63, ty = threadIdx.x >> 6;
  int r0 = blockIdx.y * 64, c0 = blockIdx.x * 64;
  #pragma unroll
  for(int i = 0; i < 16; i++){
    int r = ty*16 + i;
    tile[r][tx] = src[(size_t)(r0+r)*C + c0 + tx];
  }
  __syncthreads();
  #pragma unroll
  for(int i = 0; i < 16; i++){
    int r = ty*16 + i;
    dst[(size_t)(c0+r)*R + r0 + tx] = f2b(tile[tx][r]);
  }
}

// ------- V [BH][S][HD] bf16 -> Vt [BH][HD][S] bf16 -------
__global__ __launch_bounds__(256) void vtrans_kernel(const u16* __restrict__ V, u16* __restrict__ Vt){
  __shared__ u16 t2[64][66];
  int tx = threadIdx.x & 63, ty = threadIdx.x >> 6;
  int bh = blockIdx.y, s0 = blockIdx.x * 64;
  const u16* src = V + (size_t)bh * S_ * HD_;
  u16* dst = Vt + (size_t)bh * HD_ * S_;
  #pragma unroll
  for(int i = 0; i < 16; i++){
    int r = ty*16 + i;
    t2[r][tx] = src[(size_t)(s0+r)*HD_ + tx];
  }
  __syncthreads();
  #pragma unroll
  for(int i = 0; i < 16; i++){
    int hd = ty*16 + i;
    dst[(size_t)hd*S_ + s0 + tx] = t2[tx][hd];
  }
}

// ------- GEMM (m97 structure): A [M][K] bf16 x Bt [N][K] bf16 -------
// MODE 0: epilogue scatters to Q (x0.125), K, V in [B,H,S,HD] bf16; bias = b_qkv[col]
// MODE 1: epilogue writes f32 out[row*N+col] + bias[col]
template<int MODE>
__global__ __launch_bounds__(256) void gemm_kernel(const u16* __restrict__ A,
    const u16* __restrict__ Bt, const float* __restrict__ bias,
    u16* __restrict__ o0, u16* __restrict__ o1, u16* __restrict__ o2,
    int K, int N){
  __shared__ u16 As[128*32];
  __shared__ u16 Bs[128*32];
  int tid = threadIdx.x, w = tid >> 6, lane = tid & 63;
  int m0 = blockIdx.y * 128, n0 = blockIdx.x * 128;
  int wm = w >> 1, wn = w & 1;
  f32x4 z = {0.f, 0.f, 0.f, 0.f};
  f32x4 acc[4][4];
  #pragma unroll
  for(int r = 0; r < 4; r++)
    #pragma unroll
    for(int c = 0; c < 4; c++) acc[r][c] = z;
  int srow = lane >> 2, sch = (lane & 3) * 8;
  const u16* Ag = A + (size_t)m0 * K + (size_t)srow * K + sch;
  const u16* Bg = Bt + (size_t)n0 * K + (size_t)srow * K + sch;
  for(int kt = 0; kt < K; kt += 32){
    __syncthreads();
    #pragma unroll
    for(int i = 0; i < 2; i++){
      int rb = w*32 + i*16;
      gl_lds16(Ag + (size_t)rb*K + kt, &As[rb*32]);
      gl_lds16(Bg + (size_t)rb*K + kt, &Bs[rb*32]);
    }
    __syncthreads();
    int kc = (lane >> 4) * 8;
    int ar = wm*64 + (lane & 15);
    int bc = wn*64 + (lane & 15);
    short8 af[4], bfr[4];
    #pragma unroll
    for(int r = 0; r < 4; r++) af[r] = *(const short8*)&As[(ar + r*16)*32 + kc];
    #pragma unroll
    for(int c = 0; c < 4; c++) bfr[c] = *(const short8*)&Bs[(bc + c*16)*32 + kc];
    #pragma unroll
    for(int r = 0; r < 4; r++)
      #pragma unroll
      for(int c = 0; c < 4; c++)
        acc[r][c] = __builtin_amdgcn_mfma_f32_16x16x32_bf16(af[r], bfr[c], acc[r][c], 0, 0, 0);
  }
  #pragma unroll
  for(int r = 0; r < 4; r++){
    #pragma unroll
    for(int c = 0; c < 4; c++){
      #pragma unroll
      for(int q = 0; q < 4; q++){
        int row = m0 + wm*64 + r*16 + (lane >> 4)*4 + q;
        int col = n0 + wn*64 + c*16 + (lane & 15);
        float v = acc[r][c][q] + bias[col];
        if(MODE == 0){
          int h = col / 192, rr = col - h*192;
          int b = row >> 11, s = row & (S_ - 1);
          size_t base = ((size_t)(b*H_ + h)*S_ + s) * HD_;
          if(rr < 64)        o0[base + rr]       = f2b(v * 0.125f);
          else if(rr < 128)  o1[base + rr - 64]  = f2b(v);
          else               o2[base + rr - 128] = f2b(v);
        } else {
          ((float*)o0)[(size_t)row * N + col] = v;   // f32 final output
        }
      }
    }
  }
}

// ------- causal flash attention, paired q-strips + 2-phase pipeline -------
// Q,K [BH][S][HD] bf16, Vt [BH][HD][S] bf16 -> O [B,S,H,HD] bf16
// Block = (pair pi, bh): strips ta=pi (64 rows), tb=31-pi. One kv sweep 0..tb,
// strip A updated while kt<=ta. Double-buffered K/V staging, 1 barrier/tile.
__global__ __launch_bounds__(256) void attn_kernel(const u16* __restrict__ Q,
    const u16* __restrict__ Kb, const u16* __restrict__ Vt, u16* __restrict__ O){
  __shared__ u16 Ks[2][64*64];
  __shared__ u16 Vs[2][64*64];
  __shared__ u16 Ps[4*16*64];
  int tid = threadIdx.x, w = tid >> 6, lane = tid & 63;
  int pi = blockIdx.x;                 // 0..15
  int bh = blockIdx.y;
  const int NT = S_ / 64;              // 32
  int ta = pi, tb = NT - 1 - pi;       // ta < tb always
  const u16* Qg = Q + (size_t)bh * S_ * HD_;
  const u16* Kg = Kb + (size_t)bh * S_ * HD_;
  const u16* Vg = Vt + (size_t)bh * HD_ * S_;
  short8 qfa[2], qfb[2];
  {
    int ra = ta*64 + w*16 + (lane & 15);
    int rb = tb*64 + w*16 + (lane & 15);
    #pragma unroll
    for(int c = 0; c < 2; c++){
      qfa[c] = *(const short8*)(Qg + (size_t)ra*HD_ + (lane >> 4)*8 + c*32);
      qfb[c] = *(const short8*)(Qg + (size_t)rb*HD_ + (lane >> 4)*8 + c*32);
    }
  }
  f32x4 z = {0.f, 0.f, 0.f, 0.f};
  f32x4 oa[4], ob[4];
  float ma[4], la[4], mb[4], lb[4];
  #pragma unroll
  for(int i = 0; i < 4; i++){
    oa[i] = z; ob[i] = z;
    ma[i] = -1e30f; la[i] = 0.f; mb[i] = -1e30f; lb[i] = 0.f;
  }
  int svrow = lane >> 3;   // 0..7
  int scb = lane & 7;      // 16B chunk within 128B row

  auto STAGE = [&](int buf, int kt){
    int kv0 = kt * 64;
    #pragma unroll
    for(int i = 0; i < 2; i++){
      int rb = (i*4 + w) * 8;
      int row = rb + svrow;
      int cbs = scb ^ (row & 7);       // pre-swizzled global source (linear LDS dest)
      gl_lds16(Kg + (size_t)(kv0 + row)*HD_ + cbs*8, &Ks[buf][rb*64]);
      gl_lds16(Vg + (size_t)row*S_ + kv0 + cbs*8, &Vs[buf][rb*64]);
    }
  };

  auto COMPUTE = [&](const short8* qf, f32x4* o, float* m_run, float* l_run,
                     int tstrip, int kt, int cur){
    const char* KsB = (const char*)Ks[cur];
    const char* VsB = (const char*)Vs[cur];
    f32x4 sf[4];
    #pragma unroll
    for(int j = 0; j < 4; j++){
      f32x4 acc = z;
      #pragma unroll
      for(int c = 0; c < 2; c++){
        int row = j*16 + (lane & 15);
        int kc16 = (lane >> 4) + c*4;
        short8 kf = *(const short8*)(KsB + row*128 + ((kc16 ^ (row & 7)) * 16));
        acc = __builtin_amdgcn_mfma_f32_16x16x32_bf16(qf[c], kf, acc, 0, 0, 0);
      }
      sf[j] = acc;
    }
    if(kt == tstrip){                  // diagonal tile: causal mask
      #pragma unroll
      for(int j = 0; j < 4; j++){
        int colk = j*16 + (lane & 15);
        #pragma unroll
        for(int q = 0; q < 4; q++){
          int rowq = w*16 + (lane >> 4)*4 + q;
          if(colk > rowq) sf[j][q] = -1e30f;
        }
      }
    }
    float al[4];
    float p[4][4];
    #pragma unroll
    for(int q = 0; q < 4; q++){
      float m = fmaxf(fmaxf(sf[0][q], sf[1][q]), fmaxf(sf[2][q], sf[3][q]));
      #pragma unroll
      for(int off = 1; off < 16; off <<= 1) m = fmaxf(m, __shfl_xor(m, off));
      float mn = fmaxf(m_run[q], m);
      al[q] = __expf(m_run[q] - mn);
      m_run[q] = mn;
      float sum = 0.f;
      #pragma unroll
      for(int j = 0; j < 4; j++){ p[j][q] = __expf(sf[j][q] - mn); sum += p[j][q]; }
      #pragma unroll
      for(int off = 1; off < 16; off <<= 1) sum += __shfl_xor(sum, off);
      l_run[q] = l_run[q]*al[q] + sum;
    }
    #pragma unroll
    for(int n = 0; n < 4; n++)
      #pragma unroll
      for(int q = 0; q < 4; q++) o[n][q] *= al[q];
    // P -> per-wave swizzled LDS (no barrier: wave-private, lgkmcnt orders)
    char* Pw = (char*)Ps + w*2048;
    #pragma unroll
    for(int j = 0; j < 4; j++)
      #pragma unroll
      for(int q = 0; q < 4; q++){
        int row = (lane >> 4)*4 + q;
        int colb = (j*16 + (lane & 15)) * 2;
        *(u16*)(Pw + ((row*128 + colb) ^ ((row & 7) << 4))) = f2b(p[j][q]);
      }
    #pragma unroll
    for(int c = 0; c < 2; c++){
      int prow = lane & 15;
      int kb = ((lane >> 4) + c*4) * 16;
      short8 pa = *(const short8*)((const char*)Pw + ((prow*128 + kb) ^ ((prow & 7) << 4)));
      #pragma unroll
      for(int n = 0; n < 4; n++){
        int vrow = n*16 + (lane & 15);
        int kc16 = (lane >> 4) + c*4;
        short8 vf = *(const short8*)(VsB + vrow*128 + ((kc16 ^ (vrow & 7)) * 16));
        o[n] = __builtin_amdgcn_mfma_f32_16x16x32_bf16(pa, vf, o[n], 0, 0, 0);
      }
    }
  };

  STAGE(0, 0);
  __syncthreads();
  int cur = 0;
  for(int kt = 0; kt <= tb; kt++){
    if(kt < tb) STAGE(cur ^ 1, kt + 1);          // prefetch next tile (in flight across compute)
    COMPUTE(qfb, ob, mb, lb, tb, kt, cur);
    if(kt <= ta) COMPUTE(qfa, oa, ma, la, ta, kt, cur);
    __syncthreads();                             // drains staging + readers done
    cur ^= 1;
  }

  int b = bh >> 4, h = bh & 15;
  float inva[4], invb[4];
  #pragma unroll
  for(int q = 0; q < 4; q++){ inva[q] = 1.f / la[q]; invb[q] = 1.f / lb[q]; }
  #pragma unroll
  for(int n = 0; n < 4; n++)
    #pragma unroll
    for(int q = 0; q < 4; q++){
      int sa = ta*64 + w*16 + (lane >> 4)*4 + q;
      int sb = tb*64 + w*16 + (lane >> 4)*4 + q;
      int hd = n*16 + (lane & 15);
      O[(((size_t)(b*S_ + sa))*H_ + h)*HD_ + hd] = f2b(oa[n][q] * inva[q]);
      O[(((size_t)(b*S_ + sb))*H_ + h)*HD_ + hd] = f2b(ob[n][q] * invb[q]);
    }
}

extern "C" void kernel_launch(void* const* d_in, const int* in_sizes, int n_in,
                              void* d_out, int out_size, void* d_ws, size_t ws_size,
                              hipStream_t stream){
  (void)in_sizes; (void)n_in; (void)out_size; (void)ws_size;
  const float* x    = (const float*)d_in[0];
  const float* gam  = (const float*)d_in[1];
  const float* bet  = (const float*)d_in[2];
  const float* wqkv = (const float*)d_in[3];
  const float* bqkv = (const float*)d_in[4];
  const float* wout = (const float*)d_in[5];
  const float* bout = (const float*)d_in[6];
  char* ws = (char*)d_ws;
  // layout (bytes): xn 8.4M | wqkvT 6.3M | woutT 2.1M | Q 8.4M | K 8.4M | V 8.4M | Vt 8.4M
  u16* xn    = (u16*)(ws);
  u16* wqkvT = (u16*)(ws + 8388608);
  u16* woutT = (u16*)(ws + 8388608 + 6291456);
  u16* Qb    = (u16*)(ws + 16777216);
  u16* Kb    = (u16*)(ws + 16777216 + 8388608);
  u16* Vb    = (u16*)(ws + 16777216 + 2*8388608);
  u16* Vt    = (u16*)(ws + 16777216 + 3*8388608);
  u16* attnb = xn;                      // xn dead after GEMM1 -> reuse
  float* out = (float*)d_out;           // f32 output

  ln_kernel<<<dim3(M_), dim3(256), 0, stream>>>(x, gam, bet, xn);
  tconv_kernel<<<dim3(NQKV_/64, D_/64), dim3(256), 0, stream>>>(wqkv, wqkvT, D_, NQKV_);
  tconv_kernel<<<dim3(D_/64, D_/64), dim3(256), 0, stream>>>(wout, woutT, D_, D_);
  gemm_kernel<0><<<dim3(NQKV_/128, M_/128), dim3(256), 0, stream>>>(xn, wqkvT, bqkv, Qb, Kb, Vb, D_, NQKV_);
  vtrans_kernel<<<dim3(S_/64, B_*H_), dim3(256), 0, stream>>>(Vb, Vt);
  attn_kernel<<<dim3(S_/64/2, B_*H_), dim3(256), 0, stream>>>(Qb, Kb, Vt, attnb);
  gemm_kernel<1><<<dim3(D_/128, M_/128), dim3(256), 0, stream>>>(attnb, woutT, bout, (u16*)out, nullptr, nullptr, D_, D_);
}

// Round 4
// 162.318 us; speedup vs baseline: 1.4784x; 1.0971x over previous
//
#include <hip/hip_runtime.h>
#include <hip/hip_bf16.h>
#include <stdint.h>

#define B_ 2
#define S_ 2048
#define D_ 1024
#define H_ 16
#define HD_ 64
#define M_ (B_*S_)        // 4096 rows
#define NQKV_ (H_*3*HD_)  // 3072

typedef __attribute__((ext_vector_type(8))) short short8;
typedef __attribute__((ext_vector_type(4))) float f32x4;
typedef unsigned short u16;
typedef unsigned int u32;

__device__ __forceinline__ u16 f2b(float f){
  u32 u = __float_as_uint(f);
  u32 r = (u + 0x7FFFu + ((u >> 16) & 1u)) >> 16;   // RNE f32->bf16
  return (u16)r;
}

__device__ __forceinline__ void gl_lds16(const void* g, void* l){
  __builtin_amdgcn_global_load_lds(
      (const __attribute__((address_space(1))) void*)g,
      (__attribute__((address_space(3))) void*)l, 16, 0, 0);
}

// ---------------- LayerNorm: f32 [4096][1024] -> bf16 ----------------
__global__ __launch_bounds__(256) void ln_kernel(const float* __restrict__ x,
    const float* __restrict__ gam, const float* __restrict__ bet, u16* __restrict__ xn){
  int row = blockIdx.x;
  const float4* xr = (const float4*)(x + (size_t)row * D_);
  float4 v = xr[threadIdx.x];
  float s = v.x + v.y + v.z + v.w;
  float q = v.x*v.x + v.y*v.y + v.z*v.z + v.w*v.w;
  #pragma unroll
  for(int o = 32; o > 0; o >>= 1){ s += __shfl_down(s, o); q += __shfl_down(q, o); }
  __shared__ float red[8];
  int w = threadIdx.x >> 6, lane = threadIdx.x & 63;
  if(lane == 0){ red[w] = s; red[4+w] = q; }
  __syncthreads();
  float st = red[0]+red[1]+red[2]+red[3];
  float qt = red[4]+red[5]+red[6]+red[7];
  float mu = st * (1.0f / D_);
  float inv = rsqrtf(qt * (1.0f / D_) - mu*mu + 1e-6f);
  float4 g = ((const float4*)gam)[threadIdx.x];
  float4 b = ((const float4*)bet)[threadIdx.x];
  ushort4 o4;
  o4.x = f2b((v.x-mu)*inv*g.x + b.x);
  o4.y = f2b((v.y-mu)*inv*g.y + b.y);
  o4.z = f2b((v.z-mu)*inv*g.z + b.z);
  o4.w = f2b((v.w-mu)*inv*g.w + b.w);
  ((ushort4*)(xn + (size_t)row * D_))[threadIdx.x] = o4;
}

// ------- transpose+convert: src f32 [R][C] -> dst bf16 [C][R] -------
__global__ __launch_bounds__(256) void tconv_kernel(const float* __restrict__ src,
    u16* __restrict__ dst, int R, int C){
  __shared__ float tile[64][65];
  int tx = threadIdx.x & 63, ty = threadIdx.x >> 6;
  int r0 = blockIdx.y * 64, c0 = blockIdx.x * 64;
  #pragma unroll
  for(int i = 0; i < 16; i++){
    int r = ty*16 + i;
    tile[r][tx] = src[(size_t)(r0+r)*C + c0 + tx];
  }
  __syncthreads();
  #pragma unroll
  for(int i = 0; i < 16; i++){
    int r = ty*16 + i;
    dst[(size_t)(c0+r)*R + r0 + tx] = f2b(tile[tx][r]);
  }
}

// ------- V [BH][S][HD] bf16 -> Vt [BH][HD][S] bf16 -------
__global__ __launch_bounds__(256) void vtrans_kernel(const u16* __restrict__ V, u16* __restrict__ Vt){
  __shared__ u16 t2[64][66];
  int tx = threadIdx.x & 63, ty = threadIdx.x >> 6;
  int bh = blockIdx.y, s0 = blockIdx.x * 64;
  const u16* src = V + (size_t)bh * S_ * HD_;
  u16* dst = Vt + (size_t)bh * HD_ * S_;
  #pragma unroll
  for(int i = 0; i < 16; i++){
    int r = ty*16 + i;
    t2[r][tx] = src[(size_t)(s0+r)*HD_ + tx];
  }
  __syncthreads();
  #pragma unroll
  for(int i = 0; i < 16; i++){
    int hd = ty*16 + i;
    dst[(size_t)hd*S_ + s0 + tx] = t2[tx][hd];
  }
}

// ------- GEMM (m97 structure): A [M][K] bf16 x Bt [N][K] bf16 -------
// MODE 0: epilogue scatters to Q (x0.125), K, V in [B,H,S,HD] bf16; bias = b_qkv[col]
// MODE 1: epilogue writes f32 out[row*N+col] + bias[col]
template<int MODE>
__global__ __launch_bounds__(256) void gemm_kernel(const u16* __restrict__ A,
    const u16* __restrict__ Bt, const float* __restrict__ bias,
    u16* __restrict__ o0, u16* __restrict__ o1, u16* __restrict__ o2,
    int K, int N){
  __shared__ u16 As[128*32];
  __shared__ u16 Bs[128*32];
  int tid = threadIdx.x, w = tid >> 6, lane = tid & 63;
  int m0 = blockIdx.y * 128, n0 = blockIdx.x * 128;
  int wm = w >> 1, wn = w & 1;
  f32x4 z = {0.f, 0.f, 0.f, 0.f};
  f32x4 acc[4][4];
  #pragma unroll
  for(int r = 0; r < 4; r++)
    #pragma unroll
    for(int c = 0; c < 4; c++) acc[r][c] = z;
  int srow = lane >> 2, sch = (lane & 3) * 8;
  const u16* Ag = A + (size_t)m0 * K + (size_t)srow * K + sch;
  const u16* Bg = Bt + (size_t)n0 * K + (size_t)srow * K + sch;
  for(int kt = 0; kt < K; kt += 32){
    __syncthreads();
    #pragma unroll
    for(int i = 0; i < 2; i++){
      int rb = w*32 + i*16;
      gl_lds16(Ag + (size_t)rb*K + kt, &As[rb*32]);
      gl_lds16(Bg + (size_t)rb*K + kt, &Bs[rb*32]);
    }
    __syncthreads();
    int kc = (lane >> 4) * 8;
    int ar = wm*64 + (lane & 15);
    int bc = wn*64 + (lane & 15);
    short8 af[4], bfr[4];
    #pragma unroll
    for(int r = 0; r < 4; r++) af[r] = *(const short8*)&As[(ar + r*16)*32 + kc];
    #pragma unroll
    for(int c = 0; c < 4; c++) bfr[c] = *(const short8*)&Bs[(bc + c*16)*32 + kc];
    #pragma unroll
    for(int r = 0; r < 4; r++)
      #pragma unroll
      for(int c = 0; c < 4; c++)
        acc[r][c] = __builtin_amdgcn_mfma_f32_16x16x32_bf16(af[r], bfr[c], acc[r][c], 0, 0, 0);
  }
  #pragma unroll
  for(int r = 0; r < 4; r++){
    #pragma unroll
    for(int c = 0; c < 4; c++){
      #pragma unroll
      for(int q = 0; q < 4; q++){
        int row = m0 + wm*64 + r*16 + (lane >> 4)*4 + q;
        int col = n0 + wn*64 + c*16 + (lane & 15);
        float v = acc[r][c][q] + bias[col];
        if(MODE == 0){
          int h = col / 192, rr = col - h*192;
          int b = row >> 11, s = row & (S_ - 1);
          size_t base = ((size_t)(b*H_ + h)*S_ + s) * HD_;
          if(rr < 64)        o0[base + rr]       = f2b(v * 0.125f);
          else if(rr < 128)  o1[base + rr - 64]  = f2b(v);
          else               o2[base + rr - 128] = f2b(v);
        } else {
          ((float*)o0)[(size_t)row * N + col] = v;   // f32 final output
        }
      }
    }
  }
}

// ------- causal flash attention, paired q-strips + 2-phase pipeline -------
// Swapped QK^T: S^T = mfma(K,Q) so each lane holds 16 kv-scores of ONE q
// (q = lane&15) -> softmax row-reduce = in-lane trees + 2 shfl_xor.
__global__ __launch_bounds__(256) void attn_kernel(const u16* __restrict__ Q,
    const u16* __restrict__ Kb, const u16* __restrict__ Vt, u16* __restrict__ O){
  __shared__ u16 Ks[2][64*64];
  __shared__ u16 Vs[2][64*64];
  __shared__ u16 Ps[4*16*64];
  int tid = threadIdx.x, w = tid >> 6, lane = tid & 63;
  int pi = blockIdx.x;                 // 0..15
  int bh = blockIdx.y;
  const int NT = S_ / 64;              // 32
  int ta = pi, tb = NT - 1 - pi;       // ta < tb always
  const u16* Qg = Q + (size_t)bh * S_ * HD_;
  const u16* Kg = Kb + (size_t)bh * S_ * HD_;
  const u16* Vg = Vt + (size_t)bh * HD_ * S_;
  short8 qfa[2], qfb[2];
  {
    int ra = ta*64 + w*16 + (lane & 15);
    int rb = tb*64 + w*16 + (lane & 15);
    #pragma unroll
    for(int c = 0; c < 2; c++){
      qfa[c] = *(const short8*)(Qg + (size_t)ra*HD_ + (lane >> 4)*8 + c*32);
      qfb[c] = *(const short8*)(Qg + (size_t)rb*HD_ + (lane >> 4)*8 + c*32);
    }
  }
  f32x4 z = {0.f, 0.f, 0.f, 0.f};
  f32x4 oa[4], ob[4];
  float ma = -1e30f, la = 0.f, mb = -1e30f, lb = 0.f;
  #pragma unroll
  for(int i = 0; i < 4; i++){ oa[i] = z; ob[i] = z; }
  int svrow = lane >> 3;   // 0..7
  int scb = lane & 7;      // 16B chunk within 128B row

  auto STAGE = [&](int buf, int kt){
    int kv0 = kt * 64;
    #pragma unroll
    for(int i = 0; i < 2; i++){
      int rb = (i*4 + w) * 8;
      int row = rb + svrow;
      int cbs = scb ^ (row & 7);       // pre-swizzled global source (linear LDS dest)
      gl_lds16(Kg + (size_t)(kv0 + row)*HD_ + cbs*8, &Ks[buf][rb*64]);
      gl_lds16(Vg + (size_t)row*S_ + kv0 + cbs*8, &Vs[buf][rb*64]);
    }
  };

  auto COMPUTE = [&](const short8* qf, f32x4* o, float& m_run, float& l_run,
                     int tstrip, int kt, int cur){
    const char* KsB = (const char*)Ks[cur];
    const char* VsB = (const char*)Vs[cur];
    // S^T tile: rows = kv (64), cols = q (16 per wave). Lane: q = lane&15,
    // kv = kb*16 + (lane>>4)*4 + r.
    f32x4 sf[4];
    __builtin_amdgcn_s_setprio(1);
    #pragma unroll
    for(int kb = 0; kb < 4; kb++){
      f32x4 acc = z;
      #pragma unroll
      for(int c = 0; c < 2; c++){
        int row = kb*16 + (lane & 15);
        int kc16 = (lane >> 4) + c*4;
        short8 kf = *(const short8*)(KsB + row*128 + ((kc16 ^ (row & 7)) * 16));
        acc = __builtin_amdgcn_mfma_f32_16x16x32_bf16(kf, qf[c], acc, 0, 0, 0);
      }
      sf[kb] = acc;
    }
    __builtin_amdgcn_s_setprio(0);
    if(kt == tstrip){                  // diagonal tile: causal mask
      int qo = w*16 + (lane & 15);
      #pragma unroll
      for(int kb = 0; kb < 4; kb++)
        #pragma unroll
        for(int r = 0; r < 4; r++){
          int kvo = kb*16 + (lane >> 4)*4 + r;
          if(kvo > qo) sf[kb][r] = -1e30f;
        }
    }
    // online softmax for q = lane&15: in-lane trees + 2 cross-group shfl
    float t0 = fmaxf(fmaxf(sf[0][0], sf[0][1]), fmaxf(sf[0][2], sf[0][3]));
    float t1 = fmaxf(fmaxf(sf[1][0], sf[1][1]), fmaxf(sf[1][2], sf[1][3]));
    float t2 = fmaxf(fmaxf(sf[2][0], sf[2][1]), fmaxf(sf[2][2], sf[2][3]));
    float t3 = fmaxf(fmaxf(sf[3][0], sf[3][1]), fmaxf(sf[3][2], sf[3][3]));
    float m = fmaxf(fmaxf(t0, t1), fmaxf(t2, t3));
    m = fmaxf(m, __shfl_xor(m, 16));
    m = fmaxf(m, __shfl_xor(m, 32));
    float mn = fmaxf(m_run, m);
    float al = __expf(m_run - mn);
    m_run = mn;
    float p[4][4];
    #pragma unroll
    for(int kb = 0; kb < 4; kb++)
      #pragma unroll
      for(int r = 0; r < 4; r++) p[kb][r] = __expf(sf[kb][r] - mn);
    float s0 = (p[0][0]+p[0][1]) + (p[0][2]+p[0][3]);
    float s1 = (p[1][0]+p[1][1]) + (p[1][2]+p[1][3]);
    float s2 = (p[2][0]+p[2][1]) + (p[2][2]+p[2][3]);
    float s3 = (p[3][0]+p[3][1]) + (p[3][2]+p[3][3]);
    float sum = (s0+s1) + (s2+s3);
    sum += __shfl_xor(sum, 16);
    sum += __shfl_xor(sum, 32);
    l_run = l_run * al + sum;
    // broadcast al to this lane's O rows (q_row = (lane>>4)*4 + r)
    float alr[4];
    #pragma unroll
    for(int r = 0; r < 4; r++) alr[r] = __shfl(al, (lane >> 4)*4 + r);
    #pragma unroll
    for(int n = 0; n < 4; n++)
      #pragma unroll
      for(int q = 0; q < 4; q++) o[n][q] *= alr[q];
    // P -> per-wave swizzled LDS: lane writes row q = lane&15, 4 packed bf16
    // per kb at kv = kb*16 + g*4 (+r).  (ds_write_b64 x4)
    char* Pw = (char*)Ps + w*2048;
    int qrow = lane & 15, g = lane >> 4;
    #pragma unroll
    for(int kb = 0; kb < 4; kb++){
      u32 lo = (u32)f2b(p[kb][0]) | ((u32)f2b(p[kb][1]) << 16);
      u32 hi = (u32)f2b(p[kb][2]) | ((u32)f2b(p[kb][3]) << 16);
      uint2 pk; pk.x = lo; pk.y = hi;
      int byt = (qrow*128 + kb*32 + g*8) ^ ((qrow & 7) << 4);
      *(uint2*)(Pw + byt) = pk;
    }
    // O += P V
    __builtin_amdgcn_s_setprio(1);
    #pragma unroll
    for(int c = 0; c < 2; c++){
      int prow = lane & 15;
      int kb16 = ((lane >> 4) + c*4) * 16;
      short8 pa = *(const short8*)((const char*)Pw + ((prow*128 + kb16) ^ ((prow & 7) << 4)));
      #pragma unroll
      for(int n = 0; n < 4; n++){
        int vrow = n*16 + (lane & 15);
        int kc16 = (lane >> 4) + c*4;
        short8 vf = *(const short8*)(VsB + vrow*128 + ((kc16 ^ (vrow & 7)) * 16));
        o[n] = __builtin_amdgcn_mfma_f32_16x16x32_bf16(pa, vf, o[n], 0, 0, 0);
      }
    }
    __builtin_amdgcn_s_setprio(0);
  };

  STAGE(0, 0);
  __syncthreads();
  int cur = 0;
  for(int kt = 0; kt <= tb; kt++){
    if(kt < tb) STAGE(cur ^ 1, kt + 1);          // prefetch next tile
    COMPUTE(qfb, ob, mb, lb, tb, kt, cur);
    if(kt <= ta) COMPUTE(qfa, oa, ma, la, ta, kt, cur);
    __syncthreads();                             // drains staging + readers done
    cur ^= 1;
  }

  int b = bh >> 4, h = bh & 15;
  float linva = 1.f / la, linvb = 1.f / lb;
  float inva[4], invb[4];
  #pragma unroll
  for(int r = 0; r < 4; r++){
    inva[r] = __shfl(linva, (lane >> 4)*4 + r);
    invb[r] = __shfl(linvb, (lane >> 4)*4 + r);
  }
  #pragma unroll
  for(int n = 0; n < 4; n++)
    #pragma unroll
    for(int q = 0; q < 4; q++){
      int sa = ta*64 + w*16 + (lane >> 4)*4 + q;
      int sb = tb*64 + w*16 + (lane >> 4)*4 + q;
      int hd = n*16 + (lane & 15);
      O[(((size_t)(b*S_ + sa))*H_ + h)*HD_ + hd] = f2b(oa[n][q] * inva[q]);
      O[(((size_t)(b*S_ + sb))*H_ + h)*HD_ + hd] = f2b(ob[n][q] * invb[q]);
    }
}

extern "C" void kernel_launch(void* const* d_in, const int* in_sizes, int n_in,
                              void* d_out, int out_size, void* d_ws, size_t ws_size,
                              hipStream_t stream){
  (void)in_sizes; (void)n_in; (void)out_size; (void)ws_size;
  const float* x    = (const float*)d_in[0];
  const float* gam  = (const float*)d_in[1];
  const float* bet  = (const float*)d_in[2];
  const float* wqkv = (const float*)d_in[3];
  const float* bqkv = (const float*)d_in[4];
  const float* wout = (const float*)d_in[5];
  const float* bout = (const float*)d_in[6];
  char* ws = (char*)d_ws;
  // layout (bytes): xn 8.4M | wqkvT 6.3M | woutT 2.1M | Q 8.4M | K 8.4M | V 8.4M | Vt 8.4M
  u16* xn    = (u16*)(ws);
  u16* wqkvT = (u16*)(ws + 8388608);
  u16* woutT = (u16*)(ws + 8388608 + 6291456);
  u16* Qb    = (u16*)(ws + 16777216);
  u16* Kb    = (u16*)(ws + 16777216 + 8388608);
  u16* Vb    = (u16*)(ws + 16777216 + 2*8388608);
  u16* Vt    = (u16*)(ws + 16777216 + 3*8388608);
  u16* attnb = xn;                      // xn dead after GEMM1 -> reuse
  float* out = (float*)d_out;           // f32 output

  ln_kernel<<<dim3(M_), dim3(256), 0, stream>>>(x, gam, bet, xn);
  tconv_kernel<<<dim3(NQKV_/64, D_/64), dim3(256), 0, stream>>>(wqkv, wqkvT, D_, NQKV_);
  tconv_kernel<<<dim3(D_/64, D_/64), dim3(256), 0, stream>>>(wout, woutT, D_, D_);
  gemm_kernel<0><<<dim3(NQKV_/128, M_/128), dim3(256), 0, stream>>>(xn, wqkvT, bqkv, Qb, Kb, Vb, D_, NQKV_);
  vtrans_kernel<<<dim3(S_/64, B_*H_), dim3(256), 0, stream>>>(Vb, Vt);
  attn_kernel<<<dim3(S_/64/2, B_*H_), dim3(256), 0, stream>>>(Qb, Kb, Vt, attnb);
  gemm_kernel<1><<<dim3(D_/128, M_/128), dim3(256), 0, stream>>>(attnb, woutT, bout, (u16*)out, nullptr, nullptr, D_, D_);
}

// Round 5
// 150.016 us; speedup vs baseline: 1.5997x; 1.0820x over previous
//
#include <hip/hip_runtime.h>
#include <hip/hip_bf16.h>
#include <stdint.h>

#define B_ 2
#define S_ 2048
#define D_ 1024
#define H_ 16
#define HD_ 64
#define M_ (B_*S_)        // 4096 rows
#define NQKV_ (H_*3*HD_)  // 3072

typedef __attribute__((ext_vector_type(8))) short short8;
typedef __attribute__((ext_vector_type(4))) float f32x4;
typedef unsigned short u16;
typedef unsigned int u32;

__device__ __forceinline__ u16 f2b(float f){
  u32 u = __float_as_uint(f);
  u32 r = (u + 0x7FFFu + ((u >> 16) & 1u)) >> 16;   // RNE f32->bf16
  return (u16)r;
}

__device__ __forceinline__ void gl_lds16(const void* g, void* l){
  __builtin_amdgcn_global_load_lds(
      (const __attribute__((address_space(1))) void*)g,
      (__attribute__((address_space(3))) void*)l, 16, 0, 0);
}

// ---------------- LayerNorm: f32 [4096][1024] -> bf16 ----------------
__global__ __launch_bounds__(256) void ln_kernel(const float* __restrict__ x,
    const float* __restrict__ gam, const float* __restrict__ bet, u16* __restrict__ xn){
  int row = blockIdx.x;
  const float4* xr = (const float4*)(x + (size_t)row * D_);
  float4 v = xr[threadIdx.x];
  float s = v.x + v.y + v.z + v.w;
  float q = v.x*v.x + v.y*v.y + v.z*v.z + v.w*v.w;
  #pragma unroll
  for(int o = 32; o > 0; o >>= 1){ s += __shfl_down(s, o); q += __shfl_down(q, o); }
  __shared__ float red[8];
  int w = threadIdx.x >> 6, lane = threadIdx.x & 63;
  if(lane == 0){ red[w] = s; red[4+w] = q; }
  __syncthreads();
  float st = red[0]+red[1]+red[2]+red[3];
  float qt = red[4]+red[5]+red[6]+red[7];
  float mu = st * (1.0f / D_);
  float inv = rsqrtf(qt * (1.0f / D_) - mu*mu + 1e-6f);
  float4 g = ((const float4*)gam)[threadIdx.x];
  float4 b = ((const float4*)bet)[threadIdx.x];
  ushort4 o4;
  o4.x = f2b((v.x-mu)*inv*g.x + b.x);
  o4.y = f2b((v.y-mu)*inv*g.y + b.y);
  o4.z = f2b((v.z-mu)*inv*g.z + b.z);
  o4.w = f2b((v.w-mu)*inv*g.w + b.w);
  ((ushort4*)(xn + (size_t)row * D_))[threadIdx.x] = o4;
}

// ------- transpose+convert: src f32 [R][C] -> dst bf16 [C][R] -------
__global__ __launch_bounds__(256) void tconv_kernel(const float* __restrict__ src,
    u16* __restrict__ dst, int R, int C){
  __shared__ float tile[64][65];
  int tx = threadIdx.x & 63, ty = threadIdx.x >> 6;
  int r0 = blockIdx.y * 64, c0 = blockIdx.x * 64;
  #pragma unroll
  for(int i = 0; i < 16; i++){
    int r = ty*16 + i;
    tile[r][tx] = src[(size_t)(r0+r)*C + c0 + tx];
  }
  __syncthreads();
  #pragma unroll
  for(int i = 0; i < 16; i++){
    int r = ty*16 + i;
    dst[(size_t)(c0+r)*R + r0 + tx] = f2b(tile[tx][r]);
  }
}

// ------- V [BH][S][HD] bf16 -> Vt [BH][HD][S] bf16 -------
__global__ __launch_bounds__(256) void vtrans_kernel(const u16* __restrict__ V, u16* __restrict__ Vt){
  __shared__ u16 t2[64][66];
  int tx = threadIdx.x & 63, ty = threadIdx.x >> 6;
  int bh = blockIdx.y, s0 = blockIdx.x * 64;
  const u16* src = V + (size_t)bh * S_ * HD_;
  u16* dst = Vt + (size_t)bh * HD_ * S_;
  #pragma unroll
  for(int i = 0; i < 16; i++){
    int r = ty*16 + i;
    t2[r][tx] = src[(size_t)(s0+r)*HD_ + tx];
  }
  __syncthreads();
  #pragma unroll
  for(int i = 0; i < 16; i++){
    int hd = ty*16 + i;
    dst[(size_t)hd*S_ + s0 + tx] = t2[tx][hd];
  }
}

// ------- GEMM, 2-phase pipelined (T3 minimum recipe): A [M][K] x Bt [N][K] bf16 -------
// MODE 0: epilogue scatters to Q (x0.125), K, V in [B,H,S,HD] bf16; bias = b_qkv[col]
// MODE 1: epilogue writes f32 out[row*N+col] + bias[col]
template<int MODE>
__global__ __launch_bounds__(256) void gemm_kernel(const u16* __restrict__ A,
    const u16* __restrict__ Bt, const float* __restrict__ bias,
    u16* __restrict__ o0, u16* __restrict__ o1, u16* __restrict__ o2,
    int K, int N){
  __shared__ u16 As[2][128*32];
  __shared__ u16 Bs[2][128*32];
  int tid = threadIdx.x, w = tid >> 6, lane = tid & 63;
  int m0 = blockIdx.y * 128, n0 = blockIdx.x * 128;
  int wm = w >> 1, wn = w & 1;
  f32x4 z = {0.f, 0.f, 0.f, 0.f};
  f32x4 acc[4][4];
  #pragma unroll
  for(int r = 0; r < 4; r++)
    #pragma unroll
    for(int c = 0; c < 4; c++) acc[r][c] = z;
  int srow = lane >> 2, sch = (lane & 3) * 8;
  const u16* Ag = A + (size_t)m0 * K + (size_t)srow * K + sch;
  const u16* Bg = Bt + (size_t)n0 * K + (size_t)srow * K + sch;

  auto STAGE = [&](int buf, int kt){
    #pragma unroll
    for(int i = 0; i < 2; i++){
      int rb = w*32 + i*16;
      gl_lds16(Ag + (size_t)rb*K + kt, &As[buf][rb*32]);
      gl_lds16(Bg + (size_t)rb*K + kt, &Bs[buf][rb*32]);
    }
  };

  int nk = K >> 5;
  STAGE(0, 0);
  __syncthreads();
  for(int t = 0; t < nk; t++){
    int cur = t & 1;
    if(t + 1 < nk) STAGE(cur ^ 1, (t + 1) * 32);   // prefetch next K-tile (in flight across compute)
    int kc = (lane >> 4) * 8;
    int ar = wm*64 + (lane & 15);
    int bc = wn*64 + (lane & 15);
    short8 af[4], bfr[4];
    #pragma unroll
    for(int r = 0; r < 4; r++) af[r] = *(const short8*)&As[cur][(ar + r*16)*32 + kc];
    #pragma unroll
    for(int c = 0; c < 4; c++) bfr[c] = *(const short8*)&Bs[cur][(bc + c*16)*32 + kc];
    #pragma unroll
    for(int r = 0; r < 4; r++)
      #pragma unroll
      for(int c = 0; c < 4; c++)
        acc[r][c] = __builtin_amdgcn_mfma_f32_16x16x32_bf16(af[r], bfr[c], acc[r][c], 0, 0, 0);
    __syncthreads();                               // drains next-tile staging + readers done
  }

  #pragma unroll
  for(int r = 0; r < 4; r++){
    #pragma unroll
    for(int c = 0; c < 4; c++){
      #pragma unroll
      for(int q = 0; q < 4; q++){
        int row = m0 + wm*64 + r*16 + (lane >> 4)*4 + q;
        int col = n0 + wn*64 + c*16 + (lane & 15);
        float v = acc[r][c][q] + bias[col];
        if(MODE == 0){
          int h = col / 192, rr = col - h*192;
          int b = row >> 11, s = row & (S_ - 1);
          size_t base = ((size_t)(b*H_ + h)*S_ + s) * HD_;
          if(rr < 64)        o0[base + rr]       = f2b(v * 0.125f);
          else if(rr < 128)  o1[base + rr - 64]  = f2b(v);
          else               o2[base + rr - 128] = f2b(v);
        } else {
          ((float*)o0)[(size_t)row * N + col] = v;   // f32 final output
        }
      }
    }
  }
}

// ------- causal flash attention, paired q-strips + 2-phase pipeline -------
// Swapped QK^T: S^T = mfma(K,Q) so each lane holds 16 kv-scores of ONE q
// (q = lane&15) -> softmax row-reduce = in-lane trees + 2 shfl_xor.
__global__ __launch_bounds__(256) void attn_kernel(const u16* __restrict__ Q,
    const u16* __restrict__ Kb, const u16* __restrict__ Vt, u16* __restrict__ O){
  __shared__ u16 Ks[2][64*64];
  __shared__ u16 Vs[2][64*64];
  __shared__ u16 Ps[4*16*64];
  int tid = threadIdx.x, w = tid >> 6, lane = tid & 63;
  int pi = blockIdx.x;                 // 0..15
  int bh = blockIdx.y;
  const int NT = S_ / 64;              // 32
  int ta = pi, tb = NT - 1 - pi;       // ta < tb always
  const u16* Qg = Q + (size_t)bh * S_ * HD_;
  const u16* Kg = Kb + (size_t)bh * S_ * HD_;
  const u16* Vg = Vt + (size_t)bh * HD_ * S_;
  short8 qfa[2], qfb[2];
  {
    int ra = ta*64 + w*16 + (lane & 15);
    int rb = tb*64 + w*16 + (lane & 15);
    #pragma unroll
    for(int c = 0; c < 2; c++){
      qfa[c] = *(const short8*)(Qg + (size_t)ra*HD_ + (lane >> 4)*8 + c*32);
      qfb[c] = *(const short8*)(Qg + (size_t)rb*HD_ + (lane >> 4)*8 + c*32);
    }
  }
  f32x4 z = {0.f, 0.f, 0.f, 0.f};
  f32x4 oa[4], ob[4];
  float ma = -1e30f, la = 0.f, mb = -1e30f, lb = 0.f;
  #pragma unroll
  for(int i = 0; i < 4; i++){ oa[i] = z; ob[i] = z; }
  int svrow = lane >> 3;   // 0..7
  int scb = lane & 7;      // 16B chunk within 128B row

  auto STAGE = [&](int buf, int kt){
    int kv0 = kt * 64;
    #pragma unroll
    for(int i = 0; i < 2; i++){
      int rb = (i*4 + w) * 8;
      int row = rb + svrow;
      int cbs = scb ^ (row & 7);       // pre-swizzled global source (linear LDS dest)
      gl_lds16(Kg + (size_t)(kv0 + row)*HD_ + cbs*8, &Ks[buf][rb*64]);
      gl_lds16(Vg + (size_t)row*S_ + kv0 + cbs*8, &Vs[buf][rb*64]);
    }
  };

  auto COMPUTE = [&](const short8* qf, f32x4* o, float& m_run, float& l_run,
                     int tstrip, int kt, int cur){
    const char* KsB = (const char*)Ks[cur];
    const char* VsB = (const char*)Vs[cur];
    // S^T tile: rows = kv (64), cols = q (16 per wave). Lane: q = lane&15,
    // kv = kb*16 + (lane>>4)*4 + r.
    f32x4 sf[4];
    __builtin_amdgcn_s_setprio(1);
    #pragma unroll
    for(int kb = 0; kb < 4; kb++){
      f32x4 acc = z;
      #pragma unroll
      for(int c = 0; c < 2; c++){
        int row = kb*16 + (lane & 15);
        int kc16 = (lane >> 4) + c*4;
        short8 kf = *(const short8*)(KsB + row*128 + ((kc16 ^ (row & 7)) * 16));
        acc = __builtin_amdgcn_mfma_f32_16x16x32_bf16(kf, qf[c], acc, 0, 0, 0);
      }
      sf[kb] = acc;
    }
    __builtin_amdgcn_s_setprio(0);
    if(kt == tstrip){                  // diagonal tile: causal mask
      int qo = w*16 + (lane & 15);
      #pragma unroll
      for(int kb = 0; kb < 4; kb++)
        #pragma unroll
        for(int r = 0; r < 4; r++){
          int kvo = kb*16 + (lane >> 4)*4 + r;
          if(kvo > qo) sf[kb][r] = -1e30f;
        }
    }
    // online softmax for q = lane&15: in-lane trees + 2 cross-group shfl
    float t0 = fmaxf(fmaxf(sf[0][0], sf[0][1]), fmaxf(sf[0][2], sf[0][3]));
    float t1 = fmaxf(fmaxf(sf[1][0], sf[1][1]), fmaxf(sf[1][2], sf[1][3]));
    float t2 = fmaxf(fmaxf(sf[2][0], sf[2][1]), fmaxf(sf[2][2], sf[2][3]));
    float t3 = fmaxf(fmaxf(sf[3][0], sf[3][1]), fmaxf(sf[3][2], sf[3][3]));
    float m = fmaxf(fmaxf(t0, t1), fmaxf(t2, t3));
    m = fmaxf(m, __shfl_xor(m, 16));
    m = fmaxf(m, __shfl_xor(m, 32));
    float mn = fmaxf(m_run, m);
    float al = __expf(m_run - mn);
    m_run = mn;
    float p[4][4];
    #pragma unroll
    for(int kb = 0; kb < 4; kb++)
      #pragma unroll
      for(int r = 0; r < 4; r++) p[kb][r] = __expf(sf[kb][r] - mn);
    float s0 = (p[0][0]+p[0][1]) + (p[0][2]+p[0][3]);
    float s1 = (p[1][0]+p[1][1]) + (p[1][2]+p[1][3]);
    float s2 = (p[2][0]+p[2][1]) + (p[2][2]+p[2][3]);
    float s3 = (p[3][0]+p[3][1]) + (p[3][2]+p[3][3]);
    float sum = (s0+s1) + (s2+s3);
    sum += __shfl_xor(sum, 16);
    sum += __shfl_xor(sum, 32);
    l_run = l_run * al + sum;
    // broadcast al to this lane's O rows (q_row = (lane>>4)*4 + r)
    float alr[4];
    #pragma unroll
    for(int r = 0; r < 4; r++) alr[r] = __shfl(al, (lane >> 4)*4 + r);
    #pragma unroll
    for(int n = 0; n < 4; n++)
      #pragma unroll
      for(int q = 0; q < 4; q++) o[n][q] *= alr[q];
    // P -> per-wave swizzled LDS: lane writes row q = lane&15, 4 packed bf16
    // per kb at kv = kb*16 + g*4 (+r).  (ds_write_b64 x4)
    char* Pw = (char*)Ps + w*2048;
    int qrow = lane & 15, g = lane >> 4;
    #pragma unroll
    for(int kb = 0; kb < 4; kb++){
      u32 lo = (u32)f2b(p[kb][0]) | ((u32)f2b(p[kb][1]) << 16);
      u32 hi = (u32)f2b(p[kb][2]) | ((u32)f2b(p[kb][3]) << 16);
      uint2 pk; pk.x = lo; pk.y = hi;
      int byt = (qrow*128 + kb*32 + g*8) ^ ((qrow & 7) << 4);
      *(uint2*)(Pw + byt) = pk;
    }
    // O += P V
    __builtin_amdgcn_s_setprio(1);
    #pragma unroll
    for(int c = 0; c < 2; c++){
      int prow = lane & 15;
      int kb16 = ((lane >> 4) + c*4) * 16;
      short8 pa = *(const short8*)((const char*)Pw + ((prow*128 + kb16) ^ ((prow & 7) << 4)));
      #pragma unroll
      for(int n = 0; n < 4; n++){
        int vrow = n*16 + (lane & 15);
        int kc16 = (lane >> 4) + c*4;
        short8 vf = *(const short8*)(VsB + vrow*128 + ((kc16 ^ (vrow & 7)) * 16));
        o[n] = __builtin_amdgcn_mfma_f32_16x16x32_bf16(pa, vf, o[n], 0, 0, 0);
      }
    }
    __builtin_amdgcn_s_setprio(0);
  };

  STAGE(0, 0);
  __syncthreads();
  int cur = 0;
  for(int kt = 0; kt <= tb; kt++){
    if(kt < tb) STAGE(cur ^ 1, kt + 1);          // prefetch next tile
    COMPUTE(qfb, ob, mb, lb, tb, kt, cur);
    if(kt <= ta) COMPUTE(qfa, oa, ma, la, ta, kt, cur);
    __syncthreads();                             // drains staging + readers done
    cur ^= 1;
  }

  int b = bh >> 4, h = bh & 15;
  float linva = 1.f / la, linvb = 1.f / lb;
  float inva[4], invb[4];
  #pragma unroll
  for(int r = 0; r < 4; r++){
    inva[r] = __shfl(linva, (lane >> 4)*4 + r);
    invb[r] = __shfl(linvb, (lane >> 4)*4 + r);
  }
  #pragma unroll
  for(int n = 0; n < 4; n++)
    #pragma unroll
    for(int q = 0; q < 4; q++){
      int sa = ta*64 + w*16 + (lane >> 4)*4 + q;
      int sb = tb*64 + w*16 + (lane >> 4)*4 + q;
      int hd = n*16 + (lane & 15);
      O[(((size_t)(b*S_ + sa))*H_ + h)*HD_ + hd] = f2b(oa[n][q] * inva[q]);
      O[(((size_t)(b*S_ + sb))*H_ + h)*HD_ + hd] = f2b(ob[n][q] * invb[q]);
    }
}

extern "C" void kernel_launch(void* const* d_in, const int* in_sizes, int n_in,
                              void* d_out, int out_size, void* d_ws, size_t ws_size,
                              hipStream_t stream){
  (void)in_sizes; (void)n_in; (void)out_size; (void)ws_size;
  const float* x    = (const float*)d_in[0];
  const float* gam  = (const float*)d_in[1];
  const float* bet  = (const float*)d_in[2];
  const float* wqkv = (const float*)d_in[3];
  const float* bqkv = (const float*)d_in[4];
  const float* wout = (const float*)d_in[5];
  const float* bout = (const float*)d_in[6];
  char* ws = (char*)d_ws;
  // layout (bytes): xn 8.4M | wqkvT 6.3M | woutT 2.1M | Q 8.4M | K 8.4M | V 8.4M | Vt 8.4M
  u16* xn    = (u16*)(ws);
  u16* wqkvT = (u16*)(ws + 8388608);
  u16* woutT = (u16*)(ws + 8388608 + 6291456);
  u16* Qb    = (u16*)(ws + 16777216);
  u16* Kb    = (u16*)(ws + 16777216 + 8388608);
  u16* Vb    = (u16*)(ws + 16777216 + 2*8388608);
  u16* Vt    = (u16*)(ws + 16777216 + 3*8388608);
  u16* attnb = xn;                      // xn dead after GEMM1 -> reuse
  float* out = (float*)d_out;           // f32 output

  ln_kernel<<<dim3(M_), dim3(256), 0, stream>>>(x, gam, bet, xn);
  tconv_kernel<<<dim3(NQKV_/64, D_/64), dim3(256), 0, stream>>>(wqkv, wqkvT, D_, NQKV_);
  tconv_kernel<<<dim3(D_/64, D_/64), dim3(256), 0, stream>>>(wout, woutT, D_, D_);
  gemm_kernel<0><<<dim3(NQKV_/128, M_/128), dim3(256), 0, stream>>>(xn, wqkvT, bqkv, Qb, Kb, Vb, D_, NQKV_);
  vtrans_kernel<<<dim3(S_/64, B_*H_), dim3(256), 0, stream>>>(Vb, Vt);
  attn_kernel<<<dim3(S_/64/2, B_*H_), dim3(256), 0, stream>>>(Qb, Kb, Vt, attnb);
  gemm_kernel<1><<<dim3(D_/128, M_/128), dim3(256), 0, stream>>>(attnb, woutT, bout, (u16*)out, nullptr, nullptr, D_, D_);
}

// Round 6
// 141.165 us; speedup vs baseline: 1.6999x; 1.0627x over previous
//
#include <hip/hip_runtime.h>
#include <hip/hip_bf16.h>
#include <stdint.h>

#define B_ 2
#define S_ 2048
#define D_ 1024
#define H_ 16
#define HD_ 64
#define M_ (B_*S_)        // 4096 rows
#define NQKV_ (H_*3*HD_)  // 3072

typedef __attribute__((ext_vector_type(8))) short short8;
typedef __attribute__((ext_vector_type(4))) float f32x4;
typedef unsigned short u16;
typedef unsigned int u32;

__device__ __forceinline__ u16 f2b(float f){
  u32 u = __float_as_uint(f);
  u32 r = (u + 0x7FFFu + ((u >> 16) & 1u)) >> 16;   // RNE f32->bf16
  return (u16)r;
}

__device__ __forceinline__ void gl_lds16(const void* g, void* l){
  __builtin_amdgcn_global_load_lds(
      (const __attribute__((address_space(1))) void*)g,
      (__attribute__((address_space(3))) void*)l, 16, 0, 0);
}

// ---------------- LayerNorm: f32 [4096][1024] -> bf16 ----------------
__global__ __launch_bounds__(256) void ln_kernel(const float* __restrict__ x,
    const float* __restrict__ gam, const float* __restrict__ bet, u16* __restrict__ xn){
  int row = blockIdx.x;
  const float4* xr = (const float4*)(x + (size_t)row * D_);
  float4 v = xr[threadIdx.x];
  float s = v.x + v.y + v.z + v.w;
  float q = v.x*v.x + v.y*v.y + v.z*v.z + v.w*v.w;
  #pragma unroll
  for(int o = 32; o > 0; o >>= 1){ s += __shfl_down(s, o); q += __shfl_down(q, o); }
  __shared__ float red[8];
  int w = threadIdx.x >> 6, lane = threadIdx.x & 63;
  if(lane == 0){ red[w] = s; red[4+w] = q; }
  __syncthreads();
  float st = red[0]+red[1]+red[2]+red[3];
  float qt = red[4]+red[5]+red[6]+red[7];
  float mu = st * (1.0f / D_);
  float inv = rsqrtf(qt * (1.0f / D_) - mu*mu + 1e-6f);
  float4 g = ((const float4*)gam)[threadIdx.x];
  float4 b = ((const float4*)bet)[threadIdx.x];
  ushort4 o4;
  o4.x = f2b((v.x-mu)*inv*g.x + b.x);
  o4.y = f2b((v.y-mu)*inv*g.y + b.y);
  o4.z = f2b((v.z-mu)*inv*g.z + b.z);
  o4.w = f2b((v.w-mu)*inv*g.w + b.w);
  ((ushort4*)(xn + (size_t)row * D_))[threadIdx.x] = o4;
}

// ------- transpose+convert: src f32 [R][C] -> dst bf16 [C][R] -------
__global__ __launch_bounds__(256) void tconv_kernel(const float* __restrict__ src,
    u16* __restrict__ dst, int R, int C){
  __shared__ float tile[64][65];
  int tx = threadIdx.x & 63, ty = threadIdx.x >> 6;
  int r0 = blockIdx.y * 64, c0 = blockIdx.x * 64;
  #pragma unroll
  for(int i = 0; i < 16; i++){
    int r = ty*16 + i;
    tile[r][tx] = src[(size_t)(r0+r)*C + c0 + tx];
  }
  __syncthreads();
  #pragma unroll
  for(int i = 0; i < 16; i++){
    int r = ty*16 + i;
    dst[(size_t)(c0+r)*R + r0 + tx] = f2b(tile[tx][r]);
  }
}

// ------- V [BH][S][HD] bf16 -> Vt [BH][HD][S] bf16 -------
__global__ __launch_bounds__(256) void vtrans_kernel(const u16* __restrict__ V, u16* __restrict__ Vt){
  __shared__ u16 t2[64][66];
  int tx = threadIdx.x & 63, ty = threadIdx.x >> 6;
  int bh = blockIdx.y, s0 = blockIdx.x * 64;
  const u16* src = V + (size_t)bh * S_ * HD_;
  u16* dst = Vt + (size_t)bh * HD_ * S_;
  #pragma unroll
  for(int i = 0; i < 16; i++){
    int r = ty*16 + i;
    t2[r][tx] = src[(size_t)(s0+r)*HD_ + tx];
  }
  __syncthreads();
  #pragma unroll
  for(int i = 0; i < 16; i++){
    int hd = ty*16 + i;
    dst[(size_t)hd*S_ + s0 + tx] = t2[tx][hd];
  }
}

// ------- GEMM, 2-phase pipelined: A [M][K] x Bt [N][K] bf16 -------
template<int MODE>
__global__ __launch_bounds__(256) void gemm_kernel(const u16* __restrict__ A,
    const u16* __restrict__ Bt, const float* __restrict__ bias,
    u16* __restrict__ o0, u16* __restrict__ o1, u16* __restrict__ o2,
    int K, int N){
  __shared__ u16 As[2][128*32];
  __shared__ u16 Bs[2][128*32];
  int tid = threadIdx.x, w = tid >> 6, lane = tid & 63;
  int m0 = blockIdx.y * 128, n0 = blockIdx.x * 128;
  int wm = w >> 1, wn = w & 1;
  f32x4 z = {0.f, 0.f, 0.f, 0.f};
  f32x4 acc[4][4];
  #pragma unroll
  for(int r = 0; r < 4; r++)
    #pragma unroll
    for(int c = 0; c < 4; c++) acc[r][c] = z;
  int srow = lane >> 2, sch = (lane & 3) * 8;
  const u16* Ag = A + (size_t)m0 * K + (size_t)srow * K + sch;
  const u16* Bg = Bt + (size_t)n0 * K + (size_t)srow * K + sch;

  auto STAGE = [&](int buf, int kt){
    #pragma unroll
    for(int i = 0; i < 2; i++){
      int rb = w*32 + i*16;
      gl_lds16(Ag + (size_t)rb*K + kt, &As[buf][rb*32]);
      gl_lds16(Bg + (size_t)rb*K + kt, &Bs[buf][rb*32]);
    }
  };

  int nk = K >> 5;
  STAGE(0, 0);
  __syncthreads();
  for(int t = 0; t < nk; t++){
    int cur = t & 1;
    if(t + 1 < nk) STAGE(cur ^ 1, (t + 1) * 32);
    int kc = (lane >> 4) * 8;
    int ar = wm*64 + (lane & 15);
    int bc = wn*64 + (lane & 15);
    short8 af[4], bfr[4];
    #pragma unroll
    for(int r = 0; r < 4; r++) af[r] = *(const short8*)&As[cur][(ar + r*16)*32 + kc];
    #pragma unroll
    for(int c = 0; c < 4; c++) bfr[c] = *(const short8*)&Bs[cur][(bc + c*16)*32 + kc];
    #pragma unroll
    for(int r = 0; r < 4; r++)
      #pragma unroll
      for(int c = 0; c < 4; c++)
        acc[r][c] = __builtin_amdgcn_mfma_f32_16x16x32_bf16(af[r], bfr[c], acc[r][c], 0, 0, 0);
    __syncthreads();
  }

  #pragma unroll
  for(int r = 0; r < 4; r++){
    #pragma unroll
    for(int c = 0; c < 4; c++){
      #pragma unroll
      for(int q = 0; q < 4; q++){
        int row = m0 + wm*64 + r*16 + (lane >> 4)*4 + q;
        int col = n0 + wn*64 + c*16 + (lane & 15);
        float v = acc[r][c][q] + bias[col];
        if(MODE == 0){
          int h = col / 192, rr = col - h*192;
          int b = row >> 11, s = row & (S_ - 1);
          size_t base = ((size_t)(b*H_ + h)*S_ + s) * HD_;
          if(rr < 64)        o0[base + rr]       = f2b(v * 0.125f);
          else if(rr < 128)  o1[base + rr - 64]  = f2b(v);
          else               o2[base + rr - 128] = f2b(v);
        } else {
          ((float*)o0)[(size_t)row * N + col] = v;   // f32 final output
        }
      }
    }
  }
}

// ======================= causal flash attention =======================
// 8 waves/block. Phase 1 (kt<=ta): waves 0-3 strip b (full kv), waves 4-7
// strip a (full kv). Phase 2 (kt>ta): waves 0-3 strip b kv-half 0, waves
// 4-7 strip b kv-half 1 (independent online partials, merged at the end).
// Block time = (ta+1) + (tb-ta)/2 = 16.5 tiles-equivalent = constant.

template<int HALF>  // -1 = full kv 0..63, 0 = kv 0..31, 1 = kv 32..63
__device__ __forceinline__ void compute_tile(
    const char* KsB, const char* VsB, char* Pw, const short8* qf,
    f32x4* o, float& m_run, float& l_run, bool diag, int lane, int wr){
  constexpr int KB0 = (HALF == 1) ? 2 : 0;
  constexpr int KBN = (HALF == -1) ? 4 : 2;
  f32x4 z = {0.f, 0.f, 0.f, 0.f};
  f32x4 sf[4];
  __builtin_amdgcn_s_setprio(1);
  #pragma unroll
  for(int kb = KB0; kb < KB0 + KBN; kb++){
    f32x4 acc = z;
    #pragma unroll
    for(int c = 0; c < 2; c++){
      int row = kb*16 + (lane & 15);
      int kc16 = (lane >> 4) + c*4;
      short8 kf = *(const short8*)(KsB + row*128 + ((kc16 ^ (row & 7)) * 16));
      acc = __builtin_amdgcn_mfma_f32_16x16x32_bf16(kf, qf[c], acc, 0, 0, 0);
    }
    sf[kb] = acc;
  }
  __builtin_amdgcn_s_setprio(0);
  if(diag){
    int qo = wr*16 + (lane & 15);
    #pragma unroll
    for(int kb = KB0; kb < KB0 + KBN; kb++)
      #pragma unroll
      for(int r = 0; r < 4; r++){
        int kvo = kb*16 + (lane >> 4)*4 + r;
        if(kvo > qo) sf[kb][r] = -1e30f;
      }
  }
  // row max; -1e28 floor makes fully-masked half-tiles yield p=0 (not exp(0))
  float m = -1e28f;
  #pragma unroll
  for(int kb = KB0; kb < KB0 + KBN; kb++)
    m = fmaxf(m, fmaxf(fmaxf(sf[kb][0], sf[kb][1]), fmaxf(sf[kb][2], sf[kb][3])));
  m = fmaxf(m, __shfl_xor(m, 16));
  m = fmaxf(m, __shfl_xor(m, 32));
  float mn = fmaxf(m_run, m);
  float al = __expf(m_run - mn);
  m_run = mn;
  float p[4][4];
  float sum = 0.f;
  #pragma unroll
  for(int kb = KB0; kb < KB0 + KBN; kb++){
    #pragma unroll
    for(int r = 0; r < 4; r++) p[kb][r] = __expf(sf[kb][r] - mn);
    sum += (p[kb][0]+p[kb][1]) + (p[kb][2]+p[kb][3]);
  }
  sum += __shfl_xor(sum, 16);
  sum += __shfl_xor(sum, 32);
  l_run = l_run * al + sum;
  float alr[4];
  #pragma unroll
  for(int r = 0; r < 4; r++) alr[r] = __shfl(al, (lane >> 4)*4 + r);
  #pragma unroll
  for(int n = 0; n < 4; n++)
    #pragma unroll
    for(int q = 0; q < 4; q++) o[n][q] *= alr[q];
  // P -> per-wave swizzled LDS (packed via v_cvt_pk_bf16_f32)
  int qrow = lane & 15, g = lane >> 4;
  #pragma unroll
  for(int kb = KB0; kb < KB0 + KBN; kb++){
    u32 lo, hi;
    asm("v_cvt_pk_bf16_f32 %0, %1, %2" : "=v"(lo) : "v"(p[kb][0]), "v"(p[kb][1]));
    asm("v_cvt_pk_bf16_f32 %0, %1, %2" : "=v"(hi) : "v"(p[kb][2]), "v"(p[kb][3]));
    uint2 pk; pk.x = lo; pk.y = hi;
    int byt = (qrow*128 + kb*32 + g*8) ^ ((qrow & 7) << 4);
    *(uint2*)(Pw + byt) = pk;
  }
  // O += P V  (PV k-chunks restricted to this HALF)
  constexpr int C0 = (HALF == 1) ? 1 : 0;
  constexpr int C1 = (HALF == 0) ? 0 : 1;
  __builtin_amdgcn_s_setprio(1);
  #pragma unroll
  for(int c = C0; c <= C1; c++){
    int prow = lane & 15;
    int kb16 = ((lane >> 4) + c*4) * 16;
    short8 pa = *(const short8*)(Pw + ((prow*128 + kb16) ^ ((prow & 7) << 4)));
    #pragma unroll
    for(int n = 0; n < 4; n++){
      int vrow = n*16 + (lane & 15);
      int kc16 = (lane >> 4) + c*4;
      short8 vf = *(const short8*)(VsB + vrow*128 + ((kc16 ^ (vrow & 7)) * 16));
      o[n] = __builtin_amdgcn_mfma_f32_16x16x32_bf16(pa, vf, o[n], 0, 0, 0);
    }
  }
  __builtin_amdgcn_s_setprio(0);
}

__global__ __launch_bounds__(512) void attn_kernel(const u16* __restrict__ Q,
    const u16* __restrict__ Kb, const u16* __restrict__ Vt, u16* __restrict__ O){
  // smem map: [0,16K) K bufs | [16K,32K) V bufs | [32K,48K) P (8 waves x 2KB)
  // merge overlay (end of kernel, K/V dead): floats at [0, ~17.2K)
  __shared__ __align__(16) char smem[49152];
  char* PsBase = smem + 32768;
  int tid = threadIdx.x, w = tid >> 6, lane = tid & 63;
  int wr = w & 3, role = w >> 2;
  int pi = blockIdx.x, bh = blockIdx.y;
  const int NT = S_ / 64;              // 32
  int ta = pi, tb = NT - 1 - pi;       // ta < tb always (pi 0..15)
  const u16* Qg = Q + (size_t)bh * S_ * HD_;
  const u16* Kg = Kb + (size_t)bh * S_ * HD_;
  const u16* Vg = Vt + (size_t)bh * HD_ * S_;
  int b = bh >> 4, h = bh & 15;

  short8 qb[2], qa[2];
  {
    int rb_ = tb*64 + wr*16 + (lane & 15);
    #pragma unroll
    for(int c = 0; c < 2; c++)
      qb[c] = *(const short8*)(Qg + (size_t)rb_*HD_ + (lane >> 4)*8 + c*32);
    if(role == 1){
      int ra_ = ta*64 + wr*16 + (lane & 15);
      #pragma unroll
      for(int c = 0; c < 2; c++)
        qa[c] = *(const short8*)(Qg + (size_t)ra_*HD_ + (lane >> 4)*8 + c*32);
    }
  }
  f32x4 z = {0.f, 0.f, 0.f, 0.f};
  f32x4 o[4];
  float m_run = -1e30f, l_run = 0.f;
  #pragma unroll
  for(int i = 0; i < 4; i++) o[i] = z;
  int svrow = lane >> 3, scb = lane & 7;

  auto STAGE = [&](int buf, int kt){
    int kv0 = kt * 64;
    int rowblk = w * 8;
    int row = rowblk + svrow;
    int cbs = scb ^ (row & 7);         // pre-swizzled global source, linear LDS dest
    gl_lds16(Kg + (size_t)(kv0 + row)*HD_ + cbs*8, smem + buf*8192 + rowblk*128);
    gl_lds16(Vg + (size_t)row*S_ + kv0 + cbs*8, smem + 16384 + buf*8192 + rowblk*128);
  };

  STAGE(0, 0);
  __syncthreads();
  int cur = 0;
  char* Pw = PsBase + w*2048;
  for(int kt = 0; kt <= tb; kt++){
    if(kt < tb) STAGE(cur ^ 1, kt + 1);
    const char* KsB = (const char*)(smem + cur*8192);
    const char* VsB = (const char*)(smem + 16384 + cur*8192);
    if(role == 0){
      if(kt <= ta) compute_tile<-1>(KsB, VsB, Pw, qb, o, m_run, l_run, false, lane, wr);
      else         compute_tile<0>(KsB, VsB, Pw, qb, o, m_run, l_run, kt == tb, lane, wr);
    } else {
      if(kt <= ta){
        compute_tile<-1>(KsB, VsB, Pw, qa, o, m_run, l_run, kt == ta, lane, wr);
        if(kt == ta){
          // strip a complete: write output, reset state for b-half-1 duty
          float linv = 1.f / l_run;
          float invr[4];
          #pragma unroll
          for(int r = 0; r < 4; r++) invr[r] = __shfl(linv, (lane >> 4)*4 + r);
          #pragma unroll
          for(int n = 0; n < 4; n++)
            #pragma unroll
            for(int r = 0; r < 4; r++){
              int s = ta*64 + wr*16 + (lane >> 4)*4 + r;
              int hd = n*16 + (lane & 15);
              O[(((size_t)(b*S_ + s))*H_ + h)*HD_ + hd] = f2b(o[n][r] * invr[r]);
            }
          m_run = -1e30f; l_run = 0.f;
          #pragma unroll
          for(int i = 0; i < 4; i++) o[i] = z;
        }
      } else {
        compute_tile<1>(KsB, VsB, Pw, qb, o, m_run, l_run, kt == tb, lane, wr);
      }
    }
    __syncthreads();
    cur ^= 1;
  }

  // merge strip-b partials: role1 (half 1) publishes, role0 merges+writes
  float* Mg = (float*)smem + wr*1072;   // 16x65 O2 + 16 m2 + 16 l2
  if(role == 1){
    #pragma unroll
    for(int n = 0; n < 4; n++)
      #pragma unroll
      for(int r = 0; r < 4; r++)
        Mg[((lane >> 4)*4 + r)*65 + n*16 + (lane & 15)] = o[n][r];
    if(lane < 16){ Mg[1040 + lane] = m_run; Mg[1056 + lane] = l_run; }
  }
  __syncthreads();
  if(role == 0){
    float F1[4], F2[4], den[4];
    #pragma unroll
    for(int r = 0; r < 4; r++){
      int row = (lane >> 4)*4 + r;
      float m1r = __shfl(m_run, row);
      float l1r = __shfl(l_run, row);
      float m2r = Mg[1040 + row];
      float l2r = Mg[1056 + row];
      float mm = fmaxf(m1r, m2r);
      F1[r] = __expf(m1r - mm);
      F2[r] = __expf(m2r - mm);
      den[r] = 1.f / (l1r*F1[r] + l2r*F2[r]);
    }
    #pragma unroll
    for(int n = 0; n < 4; n++)
      #pragma unroll
      for(int r = 0; r < 4; r++){
        int row = (lane >> 4)*4 + r;
        float o2 = Mg[row*65 + n*16 + (lane & 15)];
        float val = (o[n][r]*F1[r] + o2*F2[r]) * den[r];
        int s = tb*64 + wr*16 + row;
        int hd = n*16 + (lane & 15);
        O[(((size_t)(b*S_ + s))*H_ + h)*HD_ + hd] = f2b(val);
      }
  }
}

extern "C" void kernel_launch(void* const* d_in, const int* in_sizes, int n_in,
                              void* d_out, int out_size, void* d_ws, size_t ws_size,
                              hipStream_t stream){
  (void)in_sizes; (void)n_in; (void)out_size; (void)ws_size;
  const float* x    = (const float*)d_in[0];
  const float* gam  = (const float*)d_in[1];
  const float* bet  = (const float*)d_in[2];
  const float* wqkv = (const float*)d_in[3];
  const float* bqkv = (const float*)d_in[4];
  const float* wout = (const float*)d_in[5];
  const float* bout = (const float*)d_in[6];
  char* ws = (char*)d_ws;
  u16* xn    = (u16*)(ws);
  u16* wqkvT = (u16*)(ws + 8388608);
  u16* woutT = (u16*)(ws + 8388608 + 6291456);
  u16* Qb    = (u16*)(ws + 16777216);
  u16* Kb    = (u16*)(ws + 16777216 + 8388608);
  u16* Vb    = (u16*)(ws + 16777216 + 2*8388608);
  u16* Vt    = (u16*)(ws + 16777216 + 3*8388608);
  u16* attnb = xn;                      // xn dead after GEMM1 -> reuse
  float* out = (float*)d_out;           // f32 output

  ln_kernel<<<dim3(M_), dim3(256), 0, stream>>>(x, gam, bet, xn);
  tconv_kernel<<<dim3(NQKV_/64, D_/64), dim3(256), 0, stream>>>(wqkv, wqkvT, D_, NQKV_);
  tconv_kernel<<<dim3(D_/64, D_/64), dim3(256), 0, stream>>>(wout, woutT, D_, D_);
  gemm_kernel<0><<<dim3(NQKV_/128, M_/128), dim3(256), 0, stream>>>(xn, wqkvT, bqkv, Qb, Kb, Vb, D_, NQKV_);
  vtrans_kernel<<<dim3(S_/64, B_*H_), dim3(256), 0, stream>>>(Vb, Vt);
  attn_kernel<<<dim3(S_/64/2, B_*H_), dim3(512), 0, stream>>>(Qb, Kb, Vt, attnb);
  gemm_kernel<1><<<dim3(D_/128, M_/128), dim3(256), 0, stream>>>(attnb, woutT, bout, (u16*)out, nullptr, nullptr, D_, D_);
}

// Round 7
// 131.274 us; speedup vs baseline: 1.8280x; 1.0753x over previous
//
#include <hip/hip_runtime.h>
#include <hip/hip_bf16.h>
#include <stdint.h>

#define B_ 2
#define S_ 2048
#define D_ 1024
#define H_ 16
#define HD_ 64
#define M_ (B_*S_)        // 4096 rows
#define NQKV_ (H_*3*HD_)  // 3072

typedef __attribute__((ext_vector_type(8))) short short8;
typedef __attribute__((ext_vector_type(4))) float f32x4;
typedef unsigned short u16;
typedef unsigned int u32;

__device__ __forceinline__ u16 f2b(float f){
  u32 u = __float_as_uint(f);
  u32 r = (u + 0x7FFFu + ((u >> 16) & 1u)) >> 16;   // RNE f32->bf16
  return (u16)r;
}

__device__ __forceinline__ void gl_lds16(const void* g, void* l){
  __builtin_amdgcn_global_load_lds(
      (const __attribute__((address_space(1))) void*)g,
      (__attribute__((address_space(3))) void*)l, 16, 0, 0);
}

// ---------------- LayerNorm: f32 [4096][1024] -> bf16 ----------------
__global__ __launch_bounds__(256) void ln_kernel(const float* __restrict__ x,
    const float* __restrict__ gam, const float* __restrict__ bet, u16* __restrict__ xn){
  int row = blockIdx.x;
  const float4* xr = (const float4*)(x + (size_t)row * D_);
  float4 v = xr[threadIdx.x];
  float s = v.x + v.y + v.z + v.w;
  float q = v.x*v.x + v.y*v.y + v.z*v.z + v.w*v.w;
  #pragma unroll
  for(int o = 32; o > 0; o >>= 1){ s += __shfl_down(s, o); q += __shfl_down(q, o); }
  __shared__ float red[8];
  int w = threadIdx.x >> 6, lane = threadIdx.x & 63;
  if(lane == 0){ red[w] = s; red[4+w] = q; }
  __syncthreads();
  float st = red[0]+red[1]+red[2]+red[3];
  float qt = red[4]+red[5]+red[6]+red[7];
  float mu = st * (1.0f / D_);
  float inv = rsqrtf(qt * (1.0f / D_) - mu*mu + 1e-6f);
  float4 g = ((const float4*)gam)[threadIdx.x];
  float4 b = ((const float4*)bet)[threadIdx.x];
  ushort4 o4;
  o4.x = f2b((v.x-mu)*inv*g.x + b.x);
  o4.y = f2b((v.y-mu)*inv*g.y + b.y);
  o4.z = f2b((v.z-mu)*inv*g.z + b.z);
  o4.w = f2b((v.w-mu)*inv*g.w + b.w);
  ((ushort4*)(xn + (size_t)row * D_))[threadIdx.x] = o4;
}

// ------- transpose+convert: src f32 [R][C] -> dst bf16 [C][R] -------
__global__ __launch_bounds__(256) void tconv_kernel(const float* __restrict__ src,
    u16* __restrict__ dst, int R, int C){
  __shared__ float tile[64][65];
  int tx = threadIdx.x & 63, ty = threadIdx.x >> 6;
  int r0 = blockIdx.y * 64, c0 = blockIdx.x * 64;
  #pragma unroll
  for(int i = 0; i < 16; i++){
    int r = ty*16 + i;
    tile[r][tx] = src[(size_t)(r0+r)*C + c0 + tx];
  }
  __syncthreads();
  #pragma unroll
  for(int i = 0; i < 16; i++){
    int r = ty*16 + i;
    dst[(size_t)(c0+r)*R + r0 + tx] = f2b(tile[tx][r]);
  }
}

// ------- V [BH][S][HD] bf16 -> Vt [BH][HD][S] bf16 -------
__global__ __launch_bounds__(256) void vtrans_kernel(const u16* __restrict__ V, u16* __restrict__ Vt){
  __shared__ u16 t2[64][66];
  int tx = threadIdx.x & 63, ty = threadIdx.x >> 6;
  int bh = blockIdx.y, s0 = blockIdx.x * 64;
  const u16* src = V + (size_t)bh * S_ * HD_;
  u16* dst = Vt + (size_t)bh * HD_ * S_;
  #pragma unroll
  for(int i = 0; i < 16; i++){
    int r = ty*16 + i;
    t2[r][tx] = src[(size_t)(s0+r)*HD_ + tx];
  }
  __syncthreads();
  #pragma unroll
  for(int i = 0; i < 16; i++){
    int hd = ty*16 + i;
    dst[(size_t)hd*S_ + s0 + tx] = t2[tx][hd];
  }
}

// =========== 256x256 8-phase GEMM (T3+T4+T2+T5) for QKV projection ===========
// A [M][1024] bf16 x Bt [3072][1024] bf16. Epilogue scatters Q(x0.125),K,V.
// 512 thr = 8 waves (2M x 4N); BK=64; LDS 128KB (2 dbuf x {A,B} x 2 half x 16KB).
// Per K-tile: 4 phases, quadrants A0B0/A0B1/A1B1/A1B0; one counted vmcnt(4).
// Staging: half-tile X(t+1)/B(t+2) issued only after its slot's last-reader
// phase closed; LDS swizzle chunk^=(row&7) on stage-source and ds_read.
__global__ __launch_bounds__(512, 2) void gemm256_kernel(const u16* __restrict__ A,
    const u16* __restrict__ Bt, const float* __restrict__ bias,
    u16* __restrict__ o0, u16* __restrict__ o1, u16* __restrict__ o2){
  constexpr int K_ = 1024;
  __shared__ __align__(16) char smem[131072];  // [0,64K) A slots, [64K,128K) B slots
  int tid = threadIdx.x, w = tid >> 6, lane = tid & 63;
  int wm = w >> 2, wn = w & 3;
  // XCD-aware bijective swizzle (nwg=192, 192%8==0)
  int bid = blockIdx.y * gridDim.x + blockIdx.x;
  int nwg = gridDim.x * gridDim.y;
  int cpx = nwg >> 3;
  int swz = (bid & 7) * cpx + (bid >> 3);
  int m0 = (swz / gridDim.x) * 256, n0 = (swz % gridDim.x) * 256;

  f32x4 z = {0.f, 0.f, 0.f, 0.f};
  f32x4 acc[8][4];
  #pragma unroll
  for(int r = 0; r < 8; r++)
    #pragma unroll
    for(int c = 0; c < 4; c++) acc[r][c] = z;

  // ---- staging geometry (per thread: 2 x gl_lds of 16B per half-tile) ----
  int srow_lo = w*8 + (lane >> 3);            // row within half for l=0 (l=1: +64)
  int sch = (lane & 7) ^ (srow_lo & 7);       // pre-swizzled source chunk (involution)
  auto STAGE_A = [&](int buf, int half, int kt){
    #pragma unroll
    for(int l = 0; l < 2; l++){
      int row = l*64 + srow_lo;
      gl_lds16(A + (size_t)(m0 + half*128 + row)*K_ + kt*64 + sch*8,
               smem + (buf*2 + half)*16384 + l*8192 + w*1024);
    }
  };
  auto STAGE_B = [&](int buf, int half, int kt){
    #pragma unroll
    for(int l = 0; l < 2; l++){
      int row = l*64 + srow_lo;
      gl_lds16(Bt + (size_t)(n0 + half*128 + row)*K_ + kt*64 + sch*8,
               smem + 65536 + (buf*2 + half)*16384 + l*8192 + w*1024);
    }
  };

  // ---- ds_read geometry ----
  int ln15 = lane & 15, g = lane >> 4;
  int co0 = ((g    ) ^ (ln15 & 7)) * 16;      // k=0 16B-chunk byte (swizzled)
  int co1 = ((4 + g) ^ (ln15 & 7)) * 16;      // k=1
  auto LDA = [&](int buf, int r, int k)->short8{
    int byt = buf*32768 + wm*16384 + (r*16 + ln15)*128 + (k ? co1 : co0);
    return *(const short8*)(smem + byt);
  };
  auto LDB = [&](int buf, int c, int k)->short8{
    int byt = 65536 + buf*32768 + (wn >> 1)*16384
            + ((wn & 1)*64 + c*16 + ln15)*128 + (k ? co1 : co0);
    return *(const short8*)(smem + byt);
  };
  #define BAR()   __builtin_amdgcn_s_barrier()
  #define LGKM0() do{ asm volatile("s_waitcnt lgkmcnt(0)" ::: "memory"); \
                      __builtin_amdgcn_sched_barrier(0); }while(0)

  constexpr int nk = K_ / 64;   // 16 K-tiles
  // prologue: K-tile0 (A+B) + B(1); vmcnt(4) confirms K-tile0
  STAGE_A(0, 0, 0); STAGE_A(0, 1, 0);
  STAGE_B(0, 0, 0); STAGE_B(0, 1, 0);
  STAGE_B(1, 0, 1); STAGE_B(1, 1, 1);
  asm volatile("s_waitcnt vmcnt(4)" ::: "memory");
  __builtin_amdgcn_sched_barrier(0);
  BAR();

  #pragma unroll 2
  for(int t = 0; t < nk; t++){
    int buf = t & 1;
    int kA = (t + 1 < nk) ? t + 1 : nk - 1;   // A(t+1) -> buf^1 A slots
    int kB = (t + 2 < nk) ? t + 2 : nk - 1;   // B(t+2) -> buf   B slots
    short8 a0[4][2], a1[4][2], b0[2][2], b1[2][2];
    // ---- P0: read A0,B0 ; stage Ah0(t+1) ; mfma r0-3 x c0-1 ----
    #pragma unroll
    for(int r = 0; r < 4; r++){ a0[r][0] = LDA(buf, r, 0); a0[r][1] = LDA(buf, r, 1); }
    #pragma unroll
    for(int c = 0; c < 2; c++){ b0[c][0] = LDB(buf, c, 0); b0[c][1] = LDB(buf, c, 1); }
    STAGE_A(buf ^ 1, 0, kA);
    BAR(); LGKM0();
    __builtin_amdgcn_s_setprio(1);
    #pragma unroll
    for(int r = 0; r < 4; r++)
      #pragma unroll
      for(int c = 0; c < 2; c++){
        acc[r][c] = __builtin_amdgcn_mfma_f32_16x16x32_bf16(a0[r][0], b0[c][0], acc[r][c], 0, 0, 0);
        acc[r][c] = __builtin_amdgcn_mfma_f32_16x16x32_bf16(a0[r][1], b0[c][1], acc[r][c], 0, 0, 0);
      }
    __builtin_amdgcn_s_setprio(0);
    BAR();
    // ---- P1: read B1 ; stage Ah1(t+1) ; mfma r0-3 x c2-3 ----
    #pragma unroll
    for(int c = 0; c < 2; c++){ b1[c][0] = LDB(buf, c + 2, 0); b1[c][1] = LDB(buf, c + 2, 1); }
    STAGE_A(buf ^ 1, 1, kA);
    BAR(); LGKM0();
    __builtin_amdgcn_s_setprio(1);
    #pragma unroll
    for(int r = 0; r < 4; r++)
      #pragma unroll
      for(int c = 0; c < 2; c++){
        acc[r][c+2] = __builtin_amdgcn_mfma_f32_16x16x32_bf16(a0[r][0], b1[c][0], acc[r][c+2], 0, 0, 0);
        acc[r][c+2] = __builtin_amdgcn_mfma_f32_16x16x32_bf16(a0[r][1], b1[c][1], acc[r][c+2], 0, 0, 0);
      }
    __builtin_amdgcn_s_setprio(0);
    BAR();
    // ---- P2: read A1 ; stage Bh0(t+2) ; mfma r4-7 x c2-3 ----
    #pragma unroll
    for(int r = 0; r < 4; r++){ a1[r][0] = LDA(buf, r + 4, 0); a1[r][1] = LDA(buf, r + 4, 1); }
    STAGE_B(buf, 0, kB);
    BAR(); LGKM0();
    __builtin_amdgcn_s_setprio(1);
    #pragma unroll
    for(int r = 0; r < 4; r++)
      #pragma unroll
      for(int c = 0; c < 2; c++){
        acc[r+4][c+2] = __builtin_amdgcn_mfma_f32_16x16x32_bf16(a1[r][0], b1[c][0], acc[r+4][c+2], 0, 0, 0);
        acc[r+4][c+2] = __builtin_amdgcn_mfma_f32_16x16x32_bf16(a1[r][1], b1[c][1], acc[r+4][c+2], 0, 0, 0);
      }
    __builtin_amdgcn_s_setprio(0);
    BAR();
    // ---- P3: stage Bh1(t+2) ; mfma r4-7 x c0-1 ; vmcnt(4) ----
    STAGE_B(buf, 1, kB);
    BAR();
    __builtin_amdgcn_s_setprio(1);
    #pragma unroll
    for(int r = 0; r < 4; r++)
      #pragma unroll
      for(int c = 0; c < 2; c++){
        acc[r+4][c] = __builtin_amdgcn_mfma_f32_16x16x32_bf16(a1[r][0], b0[c][0], acc[r+4][c], 0, 0, 0);
        acc[r+4][c] = __builtin_amdgcn_mfma_f32_16x16x32_bf16(a1[r][1], b0[c][1], acc[r+4][c], 0, 0, 0);
      }
    __builtin_amdgcn_s_setprio(0);
    asm volatile("s_waitcnt vmcnt(4)" ::: "memory");   // confirms K-tile t+1 resident
    __builtin_amdgcn_sched_barrier(0);
    BAR();
  }
  #undef BAR
  #undef LGKM0

  // ---- epilogue: scatter Q(x0.125)/K/V bf16 ----
  #pragma unroll
  for(int r = 0; r < 8; r++){
    #pragma unroll
    for(int c = 0; c < 4; c++){
      #pragma unroll
      for(int q = 0; q < 4; q++){
        int row = m0 + wm*128 + r*16 + g*4 + q;
        int col = n0 + wn*64 + c*16 + ln15;
        float v = acc[r][c][q] + bias[col];
        int h = col / 192, rr = col - h*192;
        int b = row >> 11, s = row & (S_ - 1);
        size_t base = ((size_t)(b*H_ + h)*S_ + s) * HD_;
        if(rr < 64)        o0[base + rr]       = f2b(v * 0.125f);
        else if(rr < 128)  o1[base + rr - 64]  = f2b(v);
        else               o2[base + rr - 128] = f2b(v);
      }
    }
  }
}

// ------- GEMM, 2-phase pipelined 128^2 (GEMM2): A [M][K] x Bt [N][K] bf16 -------
__global__ __launch_bounds__(256) void gemm_kernel(const u16* __restrict__ A,
    const u16* __restrict__ Bt, const float* __restrict__ bias,
    float* __restrict__ out, int K, int N){
  __shared__ u16 As[2][128*32];
  __shared__ u16 Bs[2][128*32];
  int tid = threadIdx.x, w = tid >> 6, lane = tid & 63;
  int m0 = blockIdx.y * 128, n0 = blockIdx.x * 128;
  int wm = w >> 1, wn = w & 1;
  f32x4 z = {0.f, 0.f, 0.f, 0.f};
  f32x4 acc[4][4];
  #pragma unroll
  for(int r = 0; r < 4; r++)
    #pragma unroll
    for(int c = 0; c < 4; c++) acc[r][c] = z;
  int srow = lane >> 2, sch = (lane & 3) * 8;
  const u16* Ag = A + (size_t)m0 * K + (size_t)srow * K + sch;
  const u16* Bg = Bt + (size_t)n0 * K + (size_t)srow * K + sch;

  auto STAGE = [&](int buf, int kt){
    #pragma unroll
    for(int i = 0; i < 2; i++){
      int rb = w*32 + i*16;
      gl_lds16(Ag + (size_t)rb*K + kt, &As[buf][rb*32]);
      gl_lds16(Bg + (size_t)rb*K + kt, &Bs[buf][rb*32]);
    }
  };

  int nk = K >> 5;
  STAGE(0, 0);
  __syncthreads();
  for(int t = 0; t < nk; t++){
    int cur = t & 1;
    if(t + 1 < nk) STAGE(cur ^ 1, (t + 1) * 32);
    int kc = (lane >> 4) * 8;
    int ar = wm*64 + (lane & 15);
    int bc = wn*64 + (lane & 15);
    short8 af[4], bfr[4];
    #pragma unroll
    for(int r = 0; r < 4; r++) af[r] = *(const short8*)&As[cur][(ar + r*16)*32 + kc];
    #pragma unroll
    for(int c = 0; c < 4; c++) bfr[c] = *(const short8*)&Bs[cur][(bc + c*16)*32 + kc];
    #pragma unroll
    for(int r = 0; r < 4; r++)
      #pragma unroll
      for(int c = 0; c < 4; c++)
        acc[r][c] = __builtin_amdgcn_mfma_f32_16x16x32_bf16(af[r], bfr[c], acc[r][c], 0, 0, 0);
    __syncthreads();
  }

  #pragma unroll
  for(int r = 0; r < 4; r++){
    #pragma unroll
    for(int c = 0; c < 4; c++){
      #pragma unroll
      for(int q = 0; q < 4; q++){
        int row = m0 + wm*64 + r*16 + (lane >> 4)*4 + q;
        int col = n0 + wn*64 + c*16 + (lane & 15);
        out[(size_t)row * N + col] = acc[r][c][q] + bias[col];
      }
    }
  }
}

// ======================= causal flash attention =======================
// 8 waves/block. Phase 1 (kt<=ta): waves 0-3 strip b (full kv), waves 4-7
// strip a (full kv). Phase 2 (kt>ta): waves 0-3 strip b kv-half 0, waves
// 4-7 strip b kv-half 1 (independent online partials, merged at the end).

template<int HALF>  // -1 = full kv 0..63, 0 = kv 0..31, 1 = kv 32..63
__device__ __forceinline__ void compute_tile(
    const char* KsB, const char* VsB, char* Pw, const short8* qf,
    f32x4* o, float& m_run, float& l_run, bool diag, int lane, int wr){
  constexpr int KB0 = (HALF == 1) ? 2 : 0;
  constexpr int KBN = (HALF == -1) ? 4 : 2;
  f32x4 z = {0.f, 0.f, 0.f, 0.f};
  f32x4 sf[4];
  __builtin_amdgcn_s_setprio(1);
  #pragma unroll
  for(int kb = KB0; kb < KB0 + KBN; kb++){
    f32x4 acc = z;
    #pragma unroll
    for(int c = 0; c < 2; c++){
      int row = kb*16 + (lane & 15);
      int kc16 = (lane >> 4) + c*4;
      short8 kf = *(const short8*)(KsB + row*128 + ((kc16 ^ (row & 7)) * 16));
      acc = __builtin_amdgcn_mfma_f32_16x16x32_bf16(kf, qf[c], acc, 0, 0, 0);
    }
    sf[kb] = acc;
  }
  __builtin_amdgcn_s_setprio(0);
  if(diag){
    int qo = wr*16 + (lane & 15);
    #pragma unroll
    for(int kb = KB0; kb < KB0 + KBN; kb++)
      #pragma unroll
      for(int r = 0; r < 4; r++){
        int kvo = kb*16 + (lane >> 4)*4 + r;
        if(kvo > qo) sf[kb][r] = -1e30f;
      }
  }
  float m = -1e28f;
  #pragma unroll
  for(int kb = KB0; kb < KB0 + KBN; kb++)
    m = fmaxf(m, fmaxf(fmaxf(sf[kb][0], sf[kb][1]), fmaxf(sf[kb][2], sf[kb][3])));
  m = fmaxf(m, __shfl_xor(m, 16));
  m = fmaxf(m, __shfl_xor(m, 32));
  float mn = fmaxf(m_run, m);
  float al = __expf(m_run - mn);
  m_run = mn;
  float p[4][4];
  float sum = 0.f;
  #pragma unroll
  for(int kb = KB0; kb < KB0 + KBN; kb++){
    #pragma unroll
    for(int r = 0; r < 4; r++) p[kb][r] = __expf(sf[kb][r] - mn);
    sum += (p[kb][0]+p[kb][1]) + (p[kb][2]+p[kb][3]);
  }
  sum += __shfl_xor(sum, 16);
  sum += __shfl_xor(sum, 32);
  l_run = l_run * al + sum;
  float alr[4];
  #pragma unroll
  for(int r = 0; r < 4; r++) alr[r] = __shfl(al, (lane >> 4)*4 + r);
  #pragma unroll
  for(int n = 0; n < 4; n++)
    #pragma unroll
    for(int q = 0; q < 4; q++) o[n][q] *= alr[q];
  int qrow = lane & 15, g = lane >> 4;
  #pragma unroll
  for(int kb = KB0; kb < KB0 + KBN; kb++){
    u32 lo, hi;
    asm("v_cvt_pk_bf16_f32 %0, %1, %2" : "=v"(lo) : "v"(p[kb][0]), "v"(p[kb][1]));
    asm("v_cvt_pk_bf16_f32 %0, %1, %2" : "=v"(hi) : "v"(p[kb][2]), "v"(p[kb][3]));
    uint2 pk; pk.x = lo; pk.y = hi;
    int byt = (qrow*128 + kb*32 + g*8) ^ ((qrow & 7) << 4);
    *(uint2*)(Pw + byt) = pk;
  }
  constexpr int C0 = (HALF == 1) ? 1 : 0;
  constexpr int C1 = (HALF == 0) ? 0 : 1;
  __builtin_amdgcn_s_setprio(1);
  #pragma unroll
  for(int c = C0; c <= C1; c++){
    int prow = lane & 15;
    int kb16 = ((lane >> 4) + c*4) * 16;
    short8 pa = *(const short8*)(Pw + ((prow*128 + kb16) ^ ((prow & 7) << 4)));
    #pragma unroll
    for(int n = 0; n < 4; n++){
      int vrow = n*16 + (lane & 15);
      int kc16 = (lane >> 4) + c*4;
      short8 vf = *(const short8*)(VsB + vrow*128 + ((kc16 ^ (vrow & 7)) * 16));
      o[n] = __builtin_amdgcn_mfma_f32_16x16x32_bf16(pa, vf, o[n], 0, 0, 0);
    }
  }
  __builtin_amdgcn_s_setprio(0);
}

__global__ __launch_bounds__(512) void attn_kernel(const u16* __restrict__ Q,
    const u16* __restrict__ Kb, const u16* __restrict__ Vt, u16* __restrict__ O){
  __shared__ __align__(16) char smem[49152];
  char* PsBase = smem + 32768;
  int tid = threadIdx.x, w = tid >> 6, lane = tid & 63;
  int wr = w & 3, role = w >> 2;
  int pi = blockIdx.x, bh = blockIdx.y;
  const int NT = S_ / 64;              // 32
  int ta = pi, tb = NT - 1 - pi;       // ta < tb always (pi 0..15)
  const u16* Qg = Q + (size_t)bh * S_ * HD_;
  const u16* Kg = Kb + (size_t)bh * S_ * HD_;
  const u16* Vg = Vt + (size_t)bh * HD_ * S_;
  int b = bh >> 4, h = bh & 15;

  short8 qb[2], qa[2];
  {
    int rb_ = tb*64 + wr*16 + (lane & 15);
    #pragma unroll
    for(int c = 0; c < 2; c++)
      qb[c] = *(const short8*)(Qg + (size_t)rb_*HD_ + (lane >> 4)*8 + c*32);
    if(role == 1){
      int ra_ = ta*64 + wr*16 + (lane & 15);
      #pragma unroll
      for(int c = 0; c < 2; c++)
        qa[c] = *(const short8*)(Qg + (size_t)ra_*HD_ + (lane >> 4)*8 + c*32);
    }
  }
  f32x4 z = {0.f, 0.f, 0.f, 0.f};
  f32x4 o[4];
  float m_run = -1e30f, l_run = 0.f;
  #pragma unroll
  for(int i = 0; i < 4; i++) o[i] = z;
  int svrow = lane >> 3, scb = lane & 7;

  auto STAGE = [&](int buf, int kt){
    int kv0 = kt * 64;
    int rowblk = w * 8;
    int row = rowblk + svrow;
    int cbs = scb ^ (row & 7);
    gl_lds16(Kg + (size_t)(kv0 + row)*HD_ + cbs*8, smem + buf*8192 + rowblk*128);
    gl_lds16(Vg + (size_t)row*S_ + kv0 + cbs*8, smem + 16384 + buf*8192 + rowblk*128);
  };

  STAGE(0, 0);
  __syncthreads();
  int cur = 0;
  char* Pw = PsBase + w*2048;
  for(int kt = 0; kt <= tb; kt++){
    if(kt < tb) STAGE(cur ^ 1, kt + 1);
    const char* KsB = (const char*)(smem + cur*8192);
    const char* VsB = (const char*)(smem + 16384 + cur*8192);
    if(role == 0){
      if(kt <= ta) compute_tile<-1>(KsB, VsB, Pw, qb, o, m_run, l_run, false, lane, wr);
      else         compute_tile<0>(KsB, VsB, Pw, qb, o, m_run, l_run, kt == tb, lane, wr);
    } else {
      if(kt <= ta){
        compute_tile<-1>(KsB, VsB, Pw, qa, o, m_run, l_run, kt == ta, lane, wr);
        if(kt == ta){
          float linv = 1.f / l_run;
          float invr[4];
          #pragma unroll
          for(int r = 0; r < 4; r++) invr[r] = __shfl(linv, (lane >> 4)*4 + r);
          #pragma unroll
          for(int n = 0; n < 4; n++)
            #pragma unroll
            for(int r = 0; r < 4; r++){
              int s = ta*64 + wr*16 + (lane >> 4)*4 + r;
              int hd = n*16 + (lane & 15);
              O[(((size_t)(b*S_ + s))*H_ + h)*HD_ + hd] = f2b(o[n][r] * invr[r]);
            }
          m_run = -1e30f; l_run = 0.f;
          #pragma unroll
          for(int i = 0; i < 4; i++) o[i] = z;
        }
      } else {
        compute_tile<1>(KsB, VsB, Pw, qb, o, m_run, l_run, kt == tb, lane, wr);
      }
    }
    __syncthreads();
    cur ^= 1;
  }

  float* Mg = (float*)smem + wr*1072;
  if(role == 1){
    #pragma unroll
    for(int n = 0; n < 4; n++)
      #pragma unroll
      for(int r = 0; r < 4; r++)
        Mg[((lane >> 4)*4 + r)*65 + n*16 + (lane & 15)] = o[n][r];
    if(lane < 16){ Mg[1040 + lane] = m_run; Mg[1056 + lane] = l_run; }
  }
  __syncthreads();
  if(role == 0){
    float F1[4], F2[4], den[4];
    #pragma unroll
    for(int r = 0; r < 4; r++){
      int row = (lane >> 4)*4 + r;
      float m1r = __shfl(m_run, row);
      float l1r = __shfl(l_run, row);
      float m2r = Mg[1040 + row];
      float l2r = Mg[1056 + row];
      float mm = fmaxf(m1r, m2r);
      F1[r] = __expf(m1r - mm);
      F2[r] = __expf(m2r - mm);
      den[r] = 1.f / (l1r*F1[r] + l2r*F2[r]);
    }
    #pragma unroll
    for(int n = 0; n < 4; n++)
      #pragma unroll
      for(int r = 0; r < 4; r++){
        int row = (lane >> 4)*4 + r;
        float o2 = Mg[row*65 + n*16 + (lane & 15)];
        float val = (o[n][r]*F1[r] + o2*F2[r]) * den[r];
        int s = tb*64 + wr*16 + row;
        int hd = n*16 + (lane & 15);
        O[(((size_t)(b*S_ + s))*H_ + h)*HD_ + hd] = f2b(val);
      }
  }
}

extern "C" void kernel_launch(void* const* d_in, const int* in_sizes, int n_in,
                              void* d_out, int out_size, void* d_ws, size_t ws_size,
                              hipStream_t stream){
  (void)in_sizes; (void)n_in; (void)out_size; (void)ws_size;
  const float* x    = (const float*)d_in[0];
  const float* gam  = (const float*)d_in[1];
  const float* bet  = (const float*)d_in[2];
  const float* wqkv = (const float*)d_in[3];
  const float* bqkv = (const float*)d_in[4];
  const float* wout = (const float*)d_in[5];
  const float* bout = (const float*)d_in[6];
  char* ws = (char*)d_ws;
  u16* xn    = (u16*)(ws);
  u16* wqkvT = (u16*)(ws + 8388608);
  u16* woutT = (u16*)(ws + 8388608 + 6291456);
  u16* Qb    = (u16*)(ws + 16777216);
  u16* Kb    = (u16*)(ws + 16777216 + 8388608);
  u16* Vb    = (u16*)(ws + 16777216 + 2*8388608);
  u16* Vt    = (u16*)(ws + 16777216 + 3*8388608);
  u16* attnb = xn;                      // xn dead after GEMM1 -> reuse
  float* out = (float*)d_out;           // f32 output

  ln_kernel<<<dim3(M_), dim3(256), 0, stream>>>(x, gam, bet, xn);
  tconv_kernel<<<dim3(NQKV_/64, D_/64), dim3(256), 0, stream>>>(wqkv, wqkvT, D_, NQKV_);
  tconv_kernel<<<dim3(D_/64, D_/64), dim3(256), 0, stream>>>(wout, woutT, D_, D_);
  gemm256_kernel<<<dim3(NQKV_/256, M_/256), dim3(512), 0, stream>>>(xn, wqkvT, bqkv, Qb, Kb, Vb);
  vtrans_kernel<<<dim3(S_/64, B_*H_), dim3(256), 0, stream>>>(Vb, Vt);
  attn_kernel<<<dim3(S_/64/2, B_*H_), dim3(512), 0, stream>>>(Qb, Kb, Vt, attnb);
  gemm_kernel<<<dim3(D_/128, M_/128), dim3(256), 0, stream>>>(attnb, woutT, bout, out, D_, D_);
}